// Round 18
// baseline (492.426 us; speedup 1.0000x reference)
//
#include <hip/hip_runtime.h>

typedef unsigned int u32;
typedef unsigned long long u64;
typedef _Float16 f16;
typedef __attribute__((ext_vector_type(2))) _Float16 f16x2;
typedef __attribute__((ext_vector_type(4))) _Float16 f16x4;
typedef __attribute__((ext_vector_type(8))) _Float16 f16x8;
typedef __attribute__((ext_vector_type(4))) float f32x4;
typedef __attribute__((ext_vector_type(2))) double f64x2;

// Problem constants: B=2, T=2048, D=2048, LAT=512, H=16, HD=128, NKV=4, G=4,
// SEL_DIM=64, TOPK=64, NROW = 4096

__device__ __forceinline__ int suX(int jj) { return jj ^ ((jj >> 4) & 7); }

// ---------------------------------------------------------------- device: transpose+cast
__device__ __forceinline__ void dev_transpose_cast(char* smem, int bx, int by,
                                                   const float* __restrict__ in,
                                                   f16* __restrict__ out, int R, int C)
{
  float* tile = (float*)smem;  // [32][33]
  int c0 = bx * 32, r0 = by * 32;
  int tx = threadIdx.x & 31, ty = threadIdx.x >> 5;
  #pragma unroll
  for (int i = ty; i < 32; i += 8) tile[i * 33 + tx] = in[(size_t)(r0 + i) * C + c0 + tx];
  __syncthreads();
  #pragma unroll
  for (int i = ty; i < 32; i += 8) out[(size_t)(c0 + i) * R + r0 + tx] = (f16)tile[tx * 33 + i];
}

// ---------------------------------------------------------------- fusedP: weight prep
__global__ __launch_bounds__(256) void k_fusedP(const float* __restrict__ Wq, f16* __restrict__ WqT,
                                                const float* __restrict__ Wkd, f16* __restrict__ WkdT,
                                                const float* __restrict__ Wku, f16* __restrict__ WkuT,
                                                const float* __restrict__ Wo, f16* __restrict__ WoT,
                                                const float* __restrict__ x, f16* __restrict__ xh)
{
  __shared__ __align__(16) char smem[4224];
  const int id = blockIdx.x;
  if (id < 4096) {
    dev_transpose_cast(smem, id & 63, id >> 6, Wq, WqT, 2048, 2048);
  } else if (id < 5120) {
    int g = id - 4096;
    dev_transpose_cast(smem, g & 15, g >> 4, Wkd, WkdT, 2048, 512);
  } else if (id < 5632) {
    int g = id - 5120;
    dev_transpose_cast(smem, g & 31, g >> 5, Wku, WkuT, 512, 1024);
  } else if (id < 9728) {
    int g = id - 5632;
    dev_transpose_cast(smem, g & 63, g >> 6, Wo, WoT, 2048, 2048);
  } else {
    int i = (id - 9728) * 256 + threadIdx.x;
    f32x4 v = *(const f32x4*)&x[(size_t)i * 4];
    f16x4 h; h.x = (f16)v.x; h.y = (f16)v.y; h.z = (f16)v.z; h.w = (f16)v.w;
    *(f16x4*)&xh[(size_t)i * 4] = h;
  }
}

// ------------------------------------------------------------- fp64 selector weights
__global__ void k_prep_sel(const float* __restrict__ Wq, const float* __restrict__ Wkd,
                           const float* __restrict__ Wku, double* __restrict__ Bsel)
{
  const int k = blockIdx.x;   // 0..2047
  const int j = threadIdx.x;  // 0..63
  Bsel[(size_t)k * 128 + j] = (double)Wq[(size_t)k * 2048 + j];
  double s = 0.0;
  for (int l = 0; l < 512; ++l)
    s = fma((double)Wkd[(size_t)k * 512 + l], (double)Wku[(size_t)l * 1024 + j], s);
  Bsel[(size_t)k * 128 + 64 + j] = s;
}

__global__ void k_bias_sel(const float* __restrict__ bq, const float* __restrict__ bkd,
                           const float* __restrict__ Wku, const float* __restrict__ bku,
                           double* __restrict__ bsel)
{
  int j = threadIdx.x;  // 0..127
  if (j < 64) {
    bsel[j] = (double)bq[j];
  } else {
    int jj = j - 64;
    double s = (double)bku[jj];
    for (int l = 0; l < 512; ++l)
      s = fma((double)bkd[l], (double)Wku[(size_t)l * 1024 + jj], s);
    bsel[j] = s;
  }
}

// ------------------------------------------------------------- device: fp64 selector GEMM slice
__device__ __forceinline__ void dev_sel_f64(char* smem, int bx, int by, int bz,
                                            const float* __restrict__ A,
                                            const double* __restrict__ Bsel,
                                            double* __restrict__ partial)
{
  double* Asd = (double*)smem;            // [32][33]
  double* Bsd = (double*)smem + 32 * 33;  // [32][66]
  const int m0 = bx * 32, n0 = by * 64;
  const int kbase = bz * 256, kend = kbase + 256;
  const int tid = threadIdx.x;
  const int tx = tid & 15, ty = tid >> 4;
  const int ar = tid >> 3, ac4 = (tid & 7) * 4;
  double acc[2][4] = {};

  f32x4 aN = *(const f32x4*)&A[(size_t)(m0 + ar) * 2048 + kbase + ac4];
  f64x2 bN[4];
  #pragma unroll
  for (int it = 0; it < 4; ++it) {
    int c = it * 256 + tid; int kk = c >> 5, n2 = (c & 31) * 2;
    bN[it] = *(const f64x2*)&Bsel[(size_t)(kbase + kk) * 128 + n0 + n2];
  }
  for (int k0 = kbase; k0 < kend; k0 += 32) {
    __syncthreads();
    Asd[ar * 33 + ac4] = (double)aN.x; Asd[ar * 33 + ac4 + 1] = (double)aN.y;
    Asd[ar * 33 + ac4 + 2] = (double)aN.z; Asd[ar * 33 + ac4 + 3] = (double)aN.w;
    #pragma unroll
    for (int it = 0; it < 4; ++it) {
      int c = it * 256 + tid; int kk = c >> 5, n2 = (c & 31) * 2;
      Bsd[kk * 66 + n2] = bN[it].x; Bsd[kk * 66 + n2 + 1] = bN[it].y;
    }
    __syncthreads();
    if (k0 + 32 < kend) {
      aN = *(const f32x4*)&A[(size_t)(m0 + ar) * 2048 + k0 + 32 + ac4];
      #pragma unroll
      for (int it = 0; it < 4; ++it) {
        int c = it * 256 + tid; int kk = c >> 5, n2 = (c & 31) * 2;
        bN[it] = *(const f64x2*)&Bsel[(size_t)(k0 + 32 + kk) * 128 + n0 + n2];
      }
    }
    #pragma unroll
    for (int kk = 0; kk < 32; ++kk) {
      double a0 = Asd[(ty * 2) * 33 + kk], a1 = Asd[(ty * 2 + 1) * 33 + kk];
      f64x2 b01 = *(const f64x2*)&Bsd[kk * 66 + tx * 2];
      f64x2 b23 = *(const f64x2*)&Bsd[kk * 66 + tx * 2 + 32];
      acc[0][0] = fma(a0, b01.x, acc[0][0]); acc[0][1] = fma(a0, b01.y, acc[0][1]);
      acc[0][2] = fma(a0, b23.x, acc[0][2]); acc[0][3] = fma(a0, b23.y, acc[0][3]);
      acc[1][0] = fma(a1, b01.x, acc[1][0]); acc[1][1] = fma(a1, b01.y, acc[1][1]);
      acc[1][2] = fma(a1, b23.x, acc[1][2]); acc[1][3] = fma(a1, b23.y, acc[1][3]);
    }
  }
  double* op = partial + (size_t)bz * 4096 * 128;
  #pragma unroll
  for (int i = 0; i < 2; ++i) {
    int row = m0 + ty * 2 + i;
    #pragma unroll
    for (int j = 0; j < 2; ++j) {
      op[(size_t)row * 128 + n0 + tx * 2 + j] = acc[i][j];
      op[(size_t)row * 128 + n0 + tx * 2 + 32 + j] = acc[i][j + 2];
    }
  }
}

// ------------------------------------------------------------- device: split-K reduce (8 slices)
__device__ __forceinline__ void dev_sel_reduce(int blk,
                                               const double* __restrict__ partial,
                                               const double* __restrict__ bias,
                                               double* __restrict__ qs64,
                                               double* __restrict__ ks64)
{
  const int idx = blk * 256 + threadIdx.x;
  const int row = idx >> 7, n = idx & 127;
  const size_t S = 4096 * 128;
  double v = partial[idx];
  #pragma unroll
  for (int z = 1; z < 8; ++z) v += partial[(size_t)z * S + idx];  // fixed order
  v += bias[n];
  if (n < 64) qs64[(size_t)row * 64 + n] = v;
  else        ks64[(size_t)row * 64 + (n - 64)] = v;
}

// ------------------------------------------------------------- fp64 transpose
__global__ __launch_bounds__(256) void k_transpose64(const double* __restrict__ in,
                                                     double* __restrict__ out)
{
  __shared__ double tile[32][33];
  const int bt = blockIdx.z;
  const int c0 = blockIdx.x * 32;
  const int r0 = blockIdx.y * 32;
  int tx = threadIdx.x & 31, ty = threadIdx.x >> 5;
  const double* ip = in + (size_t)bt * 2048 * 64;
  double* op = out + (size_t)bt * 64 * 2048;
  #pragma unroll
  for (int i = ty; i < 32; i += 8) tile[i][tx] = ip[(size_t)(r0 + i) * 64 + c0 + tx];
  __syncthreads();
  #pragma unroll
  for (int i = ty; i < 32; i += 8) op[(size_t)(c0 + i) * 2048 + r0 + tx] = tile[tx][i];
}

// ------------------------------------------------------------- k_score: su keys as tiled fp64 GEMM
// Block = 32 rows x 512 keys, K=64. A-tile (qs64) in LDS, read as block-uniform
// broadcasts (free); B (ksT) streamed coalesced (lane = key); 64 fp64 accumulators
// per thread, static indexing. Epilogue fuses the order-preserving u64 transform.
// Replaces the per-row streaming score phase that dominated k_topk for 6 rounds
// (zero reuse, ~1.3 GB latency-chained L2 reads; insensitive to occupancy/VALU fixes).
__global__ __launch_bounds__(256) void k_score(const double* __restrict__ qs,
                                               const double* __restrict__ ksT,
                                               u64* __restrict__ su)
{
  const int rt = blockIdx.x >> 2;       // row tile (32 rows)
  const int kc = blockIdx.x & 3;        // key chunk (512 keys)
  const int tmax = ((rt & 63) << 5) + 31;
  if (kc * 512 > tmax) return;          // causal: whole chunk beyond every row's t
  const int b = rt >> 6;
  const int tid = threadIdx.x;
  __shared__ double As[32 * 64];        // broadcast reads -> no conflicts
  {
    const double* qp = qs + (size_t)rt * 32 * 64;
    #pragma unroll
    for (int i = 0; i < 8; ++i) As[tid * 8 + i] = qp[tid * 8 + i];
  }
  __syncthreads();
  const int k0 = kc * 512 + tid;        // this thread's two keys
  const int k1 = k0 + 256;
  const double* kb = ksT + (size_t)b * 64 * 2048;
  double acc0[32] = {}, acc1[32] = {};
  for (int d = 0; d < 64; ++d) {
    const double b0 = kb[(size_t)d * 2048 + k0];
    const double b1 = kb[(size_t)d * 2048 + k1];
    #pragma unroll
    for (int r = 0; r < 32; ++r) {
      const double a = As[r * 64 + d];
      acc0[r] = fma(a, b0, acc0[r]);
      acc1[r] = fma(a, b1, acc1[r]);
    }
  }
  #pragma unroll
  for (int r = 0; r < 32; ++r) {
    const int row = rt * 32 + r;
    u64 u0 = (u64)__double_as_longlong(acc0[r]);
    u0 = (u0 >> 63) ? ~u0 : (u0 | 0x8000000000000000ull);
    su[(size_t)row * 2048 + k0] = u0;
    u64 u1 = (u64)__double_as_longlong(acc1[r]);
    u1 = (u1 >> 63) ? ~u1 : (u1 | 0x8000000000000000ull);
    su[(size_t)row * 2048 + k1] = u1;
  }
}

// ------------------------------------------------------------- device: fp16 MFMA GEMM
// Tile 128(M) x 64(N), BK=64, 4 waves, acc[4][2]. (R14/R15 proven.)
template <int MODE>
__device__ __forceinline__ void dev_gemm_bt(char* smem, int gbx, int gby, int nbx, int nby,
                                            const f16* __restrict__ A,
                                            const f16* __restrict__ BT,
                                            const float* __restrict__ bias,
                                            float* __restrict__ C, f16* __restrict__ Ch,
                                            f16* __restrict__ Kout, f16* __restrict__ Vout,
                                            const float* __restrict__ rc,
                                            const float* __restrict__ rs,
                                            int K, int lda, int ldb, int ldc)
{
  f16* As = (f16*)smem;             // 128*64
  f16* Bs = (f16*)smem + 128 * 64;  // 64*64
  const int tid = threadIdx.x;
  const int lane = tid & 63;
  const int wave = tid >> 6;
  int bx = gbx, by = gby;
  {
    const int nwg = nbx * nby;
    if ((nwg & 7) == 0) {
      const int bid = by * nbx + bx;
      const int cpx = nwg >> 3;
      const int sbid = (bid & 7) * cpx + (bid >> 3);
      bx = sbid % nbx;
      by = sbid / nbx;
    }
  }
  const int m0 = bx * 128, n0 = by * 64;
  const int wr = (wave >> 1) * 64, wc = (wave & 1) * 32;
  const int lrow = lane & 15;
  const int kgrp = (lane >> 4) * 8;
  f32x4 acc[4][2] = {};

  for (int k0 = 0; k0 < K; k0 += 64) {
    __syncthreads();
    #pragma unroll
    for (int it = 0; it < 4; ++it) {  // A: 128x64
      int c = it * 256 + tid;
      int r = c >> 3, c8 = (c & 7) * 8;
      int lbase = (it * 256 + (tid & 192)) * 8;
      const f16* ga = A + (size_t)(m0 + r) * lda + k0 + c8;
      __builtin_amdgcn_global_load_lds((const __attribute__((address_space(1))) u32*)ga,
                                       (__attribute__((address_space(3))) u32*)&As[lbase],
                                       16, 0, 0);
    }
    #pragma unroll
    for (int it = 0; it < 2; ++it) {  // B: 64x64
      int c = it * 256 + tid;
      int r = c >> 3, c8 = (c & 7) * 8;
      int lbase = (it * 256 + (tid & 192)) * 8;
      const f16* gb = BT + (size_t)(n0 + r) * ldb + k0 + c8;
      __builtin_amdgcn_global_load_lds((const __attribute__((address_space(1))) u32*)gb,
                                       (__attribute__((address_space(3))) u32*)&Bs[lbase],
                                       16, 0, 0);
    }
    __syncthreads();
    #pragma unroll
    for (int ks = 0; ks < 2; ++ks) {
      f16x8 af[4], bfr[2];
      #pragma unroll
      for (int m = 0; m < 4; ++m)
        af[m] = *(const f16x8*)&As[(wr + m * 16 + lrow) * 64 + ks * 32 + kgrp];
      #pragma unroll
      for (int n = 0; n < 2; ++n)
        bfr[n] = *(const f16x8*)&Bs[(wc + n * 16 + lrow) * 64 + ks * 32 + kgrp];
      #pragma unroll
      for (int m = 0; m < 4; ++m)
        #pragma unroll
        for (int n = 0; n < 2; ++n)
          acc[m][n] = __builtin_amdgcn_mfma_f32_16x16x32_f16(af[m], bfr[n], acc[m][n], 0, 0, 0);
    }
  }
  const int rbase = m0 + wr + (lane >> 4) * 4;  // C/D: col=lane&15, row=(lane>>4)*4+reg [m89]
  #pragma unroll
  for (int n = 0; n < 2; ++n) {
    int col = n0 + wc + n * 16 + lrow;
    float bv = bias ? bias[col] : 0.0f;
    const int ri = (col & 127) >> 1;  // rope pair index (MODE 2/3)
    #pragma unroll
    for (int m = 0; m < 4; ++m) {
      #pragma unroll
      for (int j = 0; j < 4; ++j) {
        int rowi = rbase + m * 16 + j;
        float v = acc[m][n][j] + bv;
        if (MODE == 0) {
          C[(size_t)rowi * ldc + col] = v;
        } else if (MODE == 1) {
          Ch[(size_t)rowi * ldc + col] = (f16)v;
        } else if (MODE == 2) {
          float vp = __shfl_xor(v, 1);
          int t = rowi & 2047;
          float c_ = rc[t * 64 + ri], s_ = rs[t * 64 + ri];
          float r_ = (lrow & 1) ? (vp * s_ + v * c_) : (v * c_ - vp * s_);
          Ch[(size_t)rowi * ldc + col] = (f16)r_;
        } else {  // MODE 3
          float vp = __shfl_xor(v, 1);
          if (n0 < 512) {
            int t = rowi & 2047;
            float c_ = rc[t * 64 + ri], s_ = rs[t * 64 + ri];
            float r_ = (lrow & 1) ? (vp * s_ + v * c_) : (v * c_ - vp * s_);
            Kout[(size_t)rowi * 512 + col] = (f16)r_;
          } else {
            Vout[(size_t)rowi * 512 + (col - 512)] = (f16)v;
          }
        }
      }
    }
  }
}

// ------------------------------------------------------------- RoPE tables
__global__ void k_rope_table(float* __restrict__ rc, float* __restrict__ rs)
{
  int t = blockIdx.x, i = threadIdx.x;  // 2048 x 64
  int fi = (2 * i) & 63;
  double inv = pow(10000.0, -(double)fi / 64.0);
  double a = (double)t * inv;
  rc[t * 64 + i] = (float)cos(a);
  rs[t * 64 + i] = (float)sin(a);
}

// ------------------------------------------------------------- k_select: exact top-64
// R17's PROVEN select machinery (register key cache, wave-uniform hist aggregation,
// shfl scans, deterministic position-computed emit), with the score phase replaced
// by a coalesced global->LDS stage of precomputed su keys (k_score output).
__global__ __launch_bounds__(512) void k_select(const u64* __restrict__ gsu,
                                                int* __restrict__ selcnt,
                                                int* __restrict__ selidx)
{
  const int r0 = blockIdx.x * 2;
  const int t0 = r0 & 2047, t1 = t0 + 1;
  const int tid = threadIdx.x;
  const int lane = tid & 63, wave = tid >> 6;
  if (t1 < 64) {
    for (int lr = 0; lr < 2; ++lr) {
      int t = t0 + lr;
      int* outp = selidx + (size_t)(r0 + lr) * 68;
      for (int jj = tid; jj <= t; jj += 512) outp[jj] = jj;
      if (tid == 0) selcnt[r0 + lr] = t + 1;
    }
    return;
  }
  __shared__ u64 su[2][2048];
  __shared__ unsigned hist[256];
  __shared__ unsigned wsum[8];
  __shared__ unsigned s_bsel, s_larger, s_cnt;
  __shared__ u64 s_thr;
  __shared__ int s_remfin;
  __shared__ int cand[128];
  __shared__ u64 ckey[128];

  // ---- stage su keys (coalesced reads; suX-swizzled LDS layout) ----
  {
    const u64* g0 = gsu + (size_t)r0 * 2048;
    const u64* g1 = gsu + (size_t)(r0 + 1) * 2048;
    for (int jj = tid; jj <= t1; jj += 512) {
      const int sx = suX(jj);
      if (jj <= t0) su[0][sx] = g0[jj];
      su[1][sx] = g1[jj];
    }
  }
  __syncthreads();

  const int c0 = tid * 4;  // 4 keys per thread
  for (int lr = 0; lr < 2; ++lr) {
    const int t = t0 + lr;
    int* outp = selidx + (size_t)(r0 + lr) * 68;
    const u64* S = su[lr];
    // cache this thread's 4 keys in registers
    u64 kv[4]; bool kvv[4];
    #pragma unroll
    for (int e = 0; e < 4; ++e) {
      const int jj = c0 + e;
      kvv[e] = (jj <= t);
      kv[e] = kvv[e] ? S[suX(jj)] : 0;
    }

    u64 prefix = 0;
    int remaining = 64;
    int broke = 0, sh_final = 0;
    for (int byte = 7; byte >= 0; --byte) {
      const int sh = byte * 8;
      if (tid < 256) hist[tid] = 0;
      __syncthreads();
      {
        unsigned bn[4]; bool vl[4];
        #pragma unroll
        for (int e = 0; e < 4; ++e) {
          vl[e] = kvv[e] && ((byte == 7) || (((kv[e] ^ prefix) >> (sh + 8)) == 0));
          bn[e] = (unsigned)((kv[e] >> sh) & 255);
        }
        unsigned myBin = 0xFFFFFFFFu, cntLoc = 0;
        bool localSame = true;
        #pragma unroll
        for (int e = 0; e < 4; ++e) {
          if (vl[e]) {
            if (myBin == 0xFFFFFFFFu) myBin = bn[e];
            else if (bn[e] != myBin) localSame = false;
            ++cntLoc;
          }
        }
        const bool hasValid = (cntLoc > 0);
        unsigned vmin = hasValid ? myBin : 0xFFFFFFFFu;
        unsigned vmax = hasValid ? myBin : 0u;
        unsigned csum = cntLoc;
        #pragma unroll
        for (int off = 32; off; off >>= 1) {
          unsigned a = __shfl_xor(vmin, off); vmin = a < vmin ? a : vmin;
          unsigned bmx = __shfl_xor(vmax, off); vmax = bmx > vmax ? bmx : vmax;
          csum += __shfl_xor(csum, off);
        }
        const bool anyMixed = (__ballot(hasValid && !localSame) != 0ull);
        const bool anyValid = (__ballot(hasValid) != 0ull);
        if (!anyMixed && anyValid && vmin == vmax) {
          if (lane == 0) atomicAdd(&hist[vmin], csum);  // one atomic per wave
        } else if (hasValid) {
          #pragma unroll
          for (int e = 0; e < 4; ++e) {
            if (vl[e]) {
              bool first = true;
              #pragma unroll
              for (int p = 0; p < 4; ++p)
                if (p < e && vl[p] && bn[p] == bn[e]) first = false;
              if (first) {
                unsigned c = 0;
                #pragma unroll
                for (int q = 0; q < 4; ++q)
                  if (q >= e && vl[q] && bn[q] == bn[e]) ++c;
                atomicAdd(&hist[bn[e]], c);
              }
            }
          }
        }
      }
      __syncthreads();
      unsigned inc = 0, cumAbove = 0;
      if (tid < 256) {
        const unsigned h = hist[tid];
        unsigned v = h;
        #pragma unroll
        for (int off = 1; off < 64; off <<= 1) {
          unsigned tv = __shfl_down(v, off);
          if (lane + off < 64) v += tv;
        }
        if (lane == 0) wsum[wave] = v;
        inc = v; cumAbove = h;
      }
      __syncthreads();
      if (tid < 256) {
        unsigned add = 0;
        #pragma unroll
        for (int w = 0; w < 4; ++w)
          if (w > wave) add += wsum[w];
        const unsigned h = cumAbove;
        inc += add;
        cumAbove = inc - h;
      }
      __syncthreads();
      if (tid < 256 && (int)cumAbove < remaining && (int)inc >= remaining) {
        s_bsel = (unsigned)tid;
        s_larger = cumAbove;
        s_cnt = inc - cumAbove;
      }
      __syncthreads();
      prefix |= ((u64)s_bsel << sh);
      remaining -= (int)s_larger;
      int cnt = (int)s_cnt;
      if (cnt <= 128) { broke = 1; sh_final = sh; break; }
    }
    u64 thr;
    int remfin;
    if (broke) {
      unsigned cg = 0;
      #pragma unroll
      for (int e = 0; e < 4; ++e)
        if (kvv[e] && (((kv[e] ^ prefix) >> sh_final) == 0)) ++cg;
      unsigned v = cg;
      #pragma unroll
      for (int off = 1; off < 64; off <<= 1) {
        unsigned tv = __shfl_up(v, off);
        if (lane >= off) v += tv;
      }
      __syncthreads();
      if (lane == 63) wsum[wave] = v;
      __syncthreads();
      unsigned add = 0, tot = 0;
      #pragma unroll
      for (int w = 0; w < 8; ++w) {
        tot += wsum[w];
        if (w < wave) add += wsum[w];
      }
      const int C = (int)tot;
      int pos = (int)(v + add - cg);
      __syncthreads();
      #pragma unroll
      for (int e = 0; e < 4; ++e)
        if (kvv[e] && (((kv[e] ^ prefix) >> sh_final) == 0)) cand[pos++] = c0 + e;
      __syncthreads();
      if (tid < C) ckey[tid] = S[suX(cand[tid])];
      __syncthreads();
      if (tid < C) {
        u64 k = ckey[tid];
        int g = 0, eq = 0;
        for (int j = 0; j < C; ++j) {
          g += (ckey[j] > k) ? 1 : 0;
          eq += (ckey[j] == k) ? 1 : 0;
        }
        if (g < remaining && remaining <= g + eq) {
          s_thr = k;
          s_remfin = remaining - g;
        }
      }
      __syncthreads();
      thr = s_thr;
      remfin = s_remfin;
    } else {
      thr = prefix;
      remfin = remaining;
    }
    __syncthreads();
    // ---- deterministic emit: diag, greaters asc, first remfin ties asc ----
    unsigned cg = 0, ct_ = 0;
    #pragma unroll
    for (int e = 0; e < 4; ++e) {
      if (kvv[e]) {
        cg += (kv[e] > thr) ? 1u : 0u;
        ct_ += (kv[e] == thr) ? 1u : 0u;
      }
    }
    const unsigned pack = cg | (ct_ << 16);
    {
      unsigned v = pack;
      #pragma unroll
      for (int off = 1; off < 64; off <<= 1) {
        unsigned tv = __shfl_up(v, off);
        if (lane >= off) v += tv;
      }
      if (lane == 63) wsum[wave] = v;
      __syncthreads();
      unsigned add = 0, tot = 0;
      #pragma unroll
      for (int w = 0; w < 8; ++w) {
        tot += wsum[w];
        if (w < wave) add += wsum[w];
      }
      const unsigned excl = v + add - pack;
      __syncthreads();
      const unsigned Gtot = tot & 0xFFFFu;
      const u64 ut = S[suX(t)];
      const unsigned gt = (ut > thr) ? 1u : 0u;
      const unsigned tt = (ut == thr) ? 1u : 0u;
      const int GtotX = (int)(Gtot - gt);
      int gpos = (int)(excl & 0xFFFFu);
      int tpos = (int)(excl >> 16);
      #pragma unroll
      for (int e = 0; e < 4; ++e) {
        const int jj = c0 + e;
        if (!kvv[e]) break;
        if (kv[e] > thr) {
          if (jj != t) outp[1 + gpos] = jj;
          ++gpos;
        } else if (kv[e] == thr) {
          if (jj != t && tpos < remfin) outp[1 + GtotX + tpos] = jj;
          ++tpos;
        }
      }
      if (tid == 0) {
        outp[0] = t;
        const unsigned Ttot = tot >> 16;
        int tb = (int)(Ttot - tt);
        int emitT = tb < remfin ? tb : remfin;
        selcnt[r0 + lr] = 1 + GtotX + emitT;  // 64 or 65
      }
    }
    __syncthreads();
  }
}

// ---------------------------------------------------------------- launch wrappers
// fusedA: sel_f64 splitK=8 (2048 blocks, fp64 VALU) || Wkd GEMM (256 blocks, MFMA)
__global__ __launch_bounds__(256) void k_fusedA(const float* __restrict__ x,
                                                const double* __restrict__ Bsel,
                                                double* __restrict__ partial,
                                                const f16* __restrict__ xh,
                                                const f16* __restrict__ WkdT,
                                                const float* __restrict__ bkd,
                                                f16* __restrict__ cbf)
{
  __shared__ __align__(16) char smem[25600];
  const int id = blockIdx.x;
  if (id < 2048) {
    dev_sel_f64(smem, id & 127, (id >> 7) & 1, id >> 8, x, Bsel, partial);
  } else {
    const int g = id - 2048;
    dev_gemm_bt<1>(smem, g & 31, g >> 5, 32, 8, xh, WkdT, bkd, nullptr, cbf,
                   nullptr, nullptr, nullptr, nullptr, 2048, 2048, 2048, 512);
  }
}

// fusedC: Wku GEMM (512 blocks @ BN=64) || sel_reduce (2048 blocks)
__global__ __launch_bounds__(256) void k_fusedC(const f16* __restrict__ cbf,
                                                const f16* __restrict__ WkuT,
                                                const float* __restrict__ bku,
                                                f16* __restrict__ krope, f16* __restrict__ vbf,
                                                const float* __restrict__ rc,
                                                const float* __restrict__ rs,
                                                const double* __restrict__ partial,
                                                const double* __restrict__ bsel,
                                                double* __restrict__ qs64,
                                                double* __restrict__ ks64)
{
  __shared__ __align__(16) char smem[24576];
  const int id = blockIdx.x;
  if (id < 512) {
    dev_gemm_bt<3>(smem, id & 31, id >> 5, 32, 16, cbf, WkuT, bku, nullptr, nullptr,
                   krope, vbf, rc, rs, 512, 512, 512, 1024);
  } else {
    dev_sel_reduce(id - 512, partial, bsel, qs64, ks64);
  }
}

// Wq GEMM standalone (MODE 2, grid 32x32)
__global__ __launch_bounds__(256) void k_gemmQ(const f16* __restrict__ xh,
                                               const f16* __restrict__ WqT,
                                               const float* __restrict__ bq,
                                               f16* __restrict__ qrope,
                                               const float* __restrict__ rc,
                                               const float* __restrict__ rs)
{
  __shared__ __align__(16) char smem[24576];
  dev_gemm_bt<2>(smem, blockIdx.x, blockIdx.y, 32, 32, xh, WqT, bq, nullptr, qrope,
                 nullptr, nullptr, rc, rs, 2048, 2048, 2048, 2048);
}

// Wo GEMM standalone (MODE 0, grid 32x32)
__global__ __launch_bounds__(256) void k_gemmO(const f16* __restrict__ A,
                                               const f16* __restrict__ BT,
                                               const float* __restrict__ bias,
                                               float* __restrict__ C)
{
  __shared__ __align__(16) char smem[24576];
  dev_gemm_bt<0>(smem, blockIdx.x, blockIdx.y, 32, 32, A, BT, bias, C, nullptr,
                 nullptr, nullptr, nullptr, nullptr, 2048, 2048, 2048, 2048);
}

// ------------------------------------------------------------- sparse attention (proven)
__global__ __launch_bounds__(256) void k_attn(const f16* __restrict__ qr,
                                              const f16* __restrict__ kr,
                                              const f16* __restrict__ vv,
                                              const int* __restrict__ selcnt,
                                              const int* __restrict__ selidx,
                                              f16* __restrict__ y)
{
  const int blk = blockIdx.x;  // row*4 + kvh
  const int row = blk >> 2, kvh = blk & 3;
  const int b = row >> 11;
  const int tid = threadIdx.x, lane = tid & 63, wave = tid >> 6;
  const int cnt = selcnt[row];
  __shared__ int sidx[68];
  __shared__ __align__(16) f16 Kl[65 * 128];   // chunk-XOR swizzled
  __shared__ __align__(16) f16 Vl[68 * 128];   // linear, rows [cnt,68) zeroed
  __shared__ f16 qlds[4][128];
  __shared__ __align__(4) f16 ph[4][72];       // P in f16, [cnt..72) zeroed
  if (tid < cnt) sidx[tid] = selidx[(size_t)row * 68 + tid];
  *(f16x2*)&qlds[wave][lane * 2] =
      *(const f16x2*)&qr[((size_t)row * 16 + kvh * 4 + wave) * 128 + lane * 2];
  __syncthreads();  // sidx ready

  f16x8 kreg[5], vreg[5];
  int rr[5], cc[5]; bool vld[5];
  #pragma unroll
  for (int it = 0; it < 5; ++it) {
    const int c = it * 256 + tid;
    const int r = c >> 4, ch = c & 15;
    const bool ok = (r < cnt);
    const int rsafe = ok ? sidx[r] : sidx[0];
    const size_t kbase = ((size_t)(b * 2048 + rsafe)) * 512 + kvh * 128 + ch * 8;
    kreg[it] = *(const f16x8*)&kr[kbase];
    vreg[it] = *(const f16x8*)&vv[kbase];
    rr[it] = r; cc[it] = ch; vld[it] = ok;
  }
  #pragma unroll
  for (int it = 0; it < 5; ++it) {
    if (vld[it]) {
      *(f16x8*)&Kl[rr[it] * 128 + ((cc[it] ^ (rr[it] & 15)) * 8)] = kreg[it];
      *(f16x8*)&Vl[rr[it] * 128 + cc[it] * 8] = vreg[it];
    }
  }
  for (int i = tid; i < (68 - cnt) * 64; i += 256)
    ((u32*)Vl)[cnt * 64 + i] = 0u;
  __syncthreads();

  const float SCALE = 0.08838834764831845f;  // 1/sqrt(128)
  auto dotk = [&](int r) -> float {
    const int sw = r & 15;
    float s = 0.0f;
    #pragma unroll
    for (int i = 0; i < 16; ++i) {
      f16x8 k8 = *(const f16x8*)&Kl[r * 128 + ((i ^ sw) * 8)];
      f16x8 q8 = *(const f16x8*)&qlds[wave][i * 8];
      #pragma unroll
      for (int e = 0; e < 4; ++e) {
        f16x2 ka; ka.x = k8[2 * e]; ka.y = k8[2 * e + 1];
        f16x2 qa; qa.x = q8[2 * e]; qa.y = q8[2 * e + 1];
        s = __builtin_amdgcn_fdot2(ka, qa, s, false);
      }
    }
    return s * SCALE;
  };

  float s1 = -__builtin_inff(), s2 = -__builtin_inff();
  if (lane < cnt) s1 = dotk(lane);
  if (lane + 64 < cnt) s2 = dotk(lane + 64);  // only lane 0, cnt==65
  float mx = fmaxf(s1, s2);
  #pragma unroll
  for (int off = 32; off; off >>= 1) mx = fmaxf(mx, __shfl_xor(mx, off));
  float p1 = (lane < cnt) ? __expf(s1 - mx) : 0.0f;
  float p2 = (lane + 64 < cnt) ? __expf(s2 - mx) : 0.0f;
  float l = p1 + p2;
  #pragma unroll
  for (int off = 32; off; off >>= 1) l += __shfl_xor(l, off);
  float linv = 1.0f / l;
  ph[wave][lane] = (f16)p1;
  if (lane == 0) ph[wave][64] = (f16)p2;
  if (lane >= 1 && lane < 8) ph[wave][64 + lane] = (f16)0.f;
  __syncthreads();

  float y0 = 0.0f, y1 = 0.0f;
  const int d2 = lane * 2;
  for (int j = 0; j < cnt; j += 2) {
    f16x2 pp = *(const f16x2*)&ph[wave][j];
    f16x2 va = *(const f16x2*)&Vl[(j + 0) * 128 + d2];
    f16x2 vb = *(const f16x2*)&Vl[(j + 1) * 128 + d2];
    f16x2 v0; v0.x = va.x; v0.y = vb.x;
    f16x2 v1; v1.x = va.y; v1.y = vb.y;
    y0 = __builtin_amdgcn_fdot2(pp, v0, y0, false);
    y1 = __builtin_amdgcn_fdot2(pp, v1, y1, false);
  }
  y0 *= linv; y1 *= linv;
  f16x2 o; o.x = (f16)y0; o.y = (f16)y1;
  *(f16x2*)&y[(size_t)row * 2048 + (kvh * 4 + wave) * 128 + d2] = o;
}

// ================================================================ launch
extern "C" void kernel_launch(void* const* d_in, const int* in_sizes, int n_in,
                              void* d_out, int out_size, void* d_ws, size_t ws_size,
                              hipStream_t stream)
{
  (void)in_sizes; (void)n_in; (void)out_size; (void)ws_size;
  const float* x   = (const float*)d_in[0];
  const float* Wq  = (const float*)d_in[1];
  const float* bq  = (const float*)d_in[2];
  const float* Wkd = (const float*)d_in[3];
  const float* bkd = (const float*)d_in[4];
  const float* Wku = (const float*)d_in[5];
  const float* bku = (const float*)d_in[6];
  const float* Wo  = (const float*)d_in[7];
  const float* bo  = (const float*)d_in[8];
  float* out = (float*)d_out;

  char* ws = (char*)d_ws;
  size_t o = 0;
  auto alloc = [&](size_t bytes) -> void* {
    o = (o + 255) & ~(size_t)255;
    void* p = ws + o;
    o += bytes;
    return p;
  };
  f16* WqT   = (f16*)alloc(2048ull * 2048 * 2);
  f16* WoT   = (f16*)alloc(2048ull * 2048 * 2);
  f16* WkdT  = (f16*)alloc(512ull * 2048 * 2);
  f16* WkuT  = (f16*)alloc(1024ull * 512 * 2);
  f16* xh    = (f16*)alloc(4096ull * 2048 * 2);
  f16* yh    = (f16*)alloc(4096ull * 2048 * 2);  // attention output
  f16* cbf   = (f16*)alloc(4096ull * 512 * 2);
  float* rc  = (float*)alloc(2048ull * 64 * 4);
  float* rs  = (float*)alloc(2048ull * 64 * 4);
  f16* qrope = (f16*)alloc(4096ull * 2048 * 2);
  f16* krope = (f16*)alloc(4096ull * 512 * 2);
  f16* vbf   = (f16*)alloc(4096ull * 512 * 2);
  int* selcnt = (int*)alloc(4096ull * 4);
  int* selidx = (int*)alloc(4096ull * 68 * 4);
  double* Bsel = (double*)alloc(2048ull * 128 * 8);
  double* bsel = (double*)alloc(128 * 8);
  double* qs64 = (double*)alloc(4096ull * 64 * 8);
  double* ks64 = (double*)alloc(4096ull * 64 * 8);
  double* ksT  = (double*)alloc(2ull * 64 * 2048 * 8);
  double* partial = (double*)alloc(8ull * 4096 * 128 * 8);  // 32 MiB (split-K=8)
  u64* gsu = (u64*)alloc(4096ull * 2048 * 8);               // 64 MiB score keys

  // --- selector weights + rope tables + weight prep ---
  k_prep_sel<<<2048, 64, 0, stream>>>(Wq, Wkd, Wku, Bsel);
  k_bias_sel<<<1, 128, 0, stream>>>(bq, bkd, Wku, bku, bsel);
  k_rope_table<<<2048, 64, 0, stream>>>(rc, rs);
  k_fusedP<<<17920, 256, 0, stream>>>(Wq, WqT, Wkd, WkdT, Wku, WkuT, Wo, WoT, x, xh);

  // --- fusedA: fp64 selector GEMM (split-K=8) || Wkd GEMM ---
  k_fusedA<<<2304, 256, 0, stream>>>(x, Bsel, partial, xh, WkdT, bkd, cbf);

  // --- fusedC: Wku GEMM (rope-k/V fused) || split-K reduce ---
  k_fusedC<<<2560, 256, 0, stream>>>(cbf, WkuT, bku, krope, vbf, rc, rs,
                                     partial, bsel, qs64, ks64);

  // --- ksT, then score keys as tiled fp64 GEMM ---
  k_transpose64<<<dim3(2, 64, 2), 256, 0, stream>>>(ks64, ksT);
  k_score<<<512, 256, 0, stream>>>(qs64, ksT, gsu);

  // --- Wq GEMM (rope-q fused), then select ---
  k_gemmQ<<<dim3(32, 32), 256, 0, stream>>>(xh, WqT, bq, qrope, rc, rs);
  k_select<<<2048, 512, 0, stream>>>(gsu, selcnt, selidx);

  // --- sparse attention ---
  k_attn<<<16384, 256, 0, stream>>>(qrope, krope, vbf, selcnt, selidx, yh);

  // --- output projection ---
  k_gemmO<<<dim3(32, 32), 256, 0, stream>>>(yh, WoT, bo, out);
}

// Round 19
// 481.240 us; speedup vs baseline: 1.0232x; 1.0232x over previous
//
#include <hip/hip_runtime.h>

typedef unsigned int u32;
typedef unsigned long long u64;
typedef _Float16 f16;
typedef __attribute__((ext_vector_type(2))) _Float16 f16x2;
typedef __attribute__((ext_vector_type(4))) _Float16 f16x4;
typedef __attribute__((ext_vector_type(8))) _Float16 f16x8;
typedef __attribute__((ext_vector_type(4))) float f32x4;
typedef __attribute__((ext_vector_type(2))) double f64x2;

// Problem constants: B=2, T=2048, D=2048, LAT=512, H=16, HD=128, NKV=4, G=4,
// SEL_DIM=64, TOPK=64, NROW = 4096

__device__ __forceinline__ int suX(int jj) { return jj ^ ((jj >> 4) & 7); }

// ---------------------------------------------------------------- device: transpose+cast
__device__ __forceinline__ void dev_transpose_cast(char* smem, int bx, int by,
                                                   const float* __restrict__ in,
                                                   f16* __restrict__ out, int R, int C)
{
  float* tile = (float*)smem;  // [32][33]
  int c0 = bx * 32, r0 = by * 32;
  int tx = threadIdx.x & 31, ty = threadIdx.x >> 5;
  #pragma unroll
  for (int i = ty; i < 32; i += 8) tile[i * 33 + tx] = in[(size_t)(r0 + i) * C + c0 + tx];
  __syncthreads();
  #pragma unroll
  for (int i = ty; i < 32; i += 8) out[(size_t)(c0 + i) * R + r0 + tx] = (f16)tile[tx * 33 + i];
}

// ---------------------------------------------------------------- megaP: ALL prep in one launch
// [0,4096) WqT | [4096,5120) WkdT | [5120,5632) WkuT | [5632,9728) WoT |
// [9728,17920) cast x | [17920,18432) prep_sel | 18432 bias_sel | [18433,18945) rope table
__global__ __launch_bounds__(256) void k_megaP(const float* __restrict__ Wq, f16* __restrict__ WqT,
                                               const float* __restrict__ Wkd, f16* __restrict__ WkdT,
                                               const float* __restrict__ Wku, f16* __restrict__ WkuT,
                                               const float* __restrict__ Wo, f16* __restrict__ WoT,
                                               const float* __restrict__ x, f16* __restrict__ xh,
                                               double* __restrict__ Bsel,
                                               const float* __restrict__ bq,
                                               const float* __restrict__ bkd,
                                               const float* __restrict__ bku,
                                               double* __restrict__ bsel,
                                               float* __restrict__ rc, float* __restrict__ rs)
{
  __shared__ __align__(16) char smem[4224];
  const int id = blockIdx.x;
  const int tid = threadIdx.x;
  if (id < 4096) {
    dev_transpose_cast(smem, id & 63, id >> 6, Wq, WqT, 2048, 2048);
  } else if (id < 5120) {
    int g = id - 4096;
    dev_transpose_cast(smem, g & 15, g >> 4, Wkd, WkdT, 2048, 512);
  } else if (id < 5632) {
    int g = id - 5120;
    dev_transpose_cast(smem, g & 31, g >> 5, Wku, WkuT, 512, 1024);
  } else if (id < 9728) {
    int g = id - 5632;
    dev_transpose_cast(smem, g & 63, g >> 6, Wo, WoT, 2048, 2048);
  } else if (id < 17920) {
    int i = (id - 9728) * 256 + tid;
    f32x4 v = *(const f32x4*)&x[(size_t)i * 4];
    f16x4 h; h.x = (f16)v.x; h.y = (f16)v.y; h.z = (f16)v.z; h.w = (f16)v.w;
    *(f16x4*)&xh[(size_t)i * 4] = h;
  } else if (id < 18432) {
    const int k = (id - 17920) * 4 + (tid >> 6);  // prep_sel remapped 64->256 thr
    const int j = tid & 63;
    Bsel[(size_t)k * 128 + j] = (double)Wq[(size_t)k * 2048 + j];
    double s = 0.0;
    for (int l = 0; l < 512; ++l)
      s = fma((double)Wkd[(size_t)k * 512 + l], (double)Wku[(size_t)l * 1024 + j], s);
    Bsel[(size_t)k * 128 + 64 + j] = s;
  } else if (id == 18432) {
    if (tid < 128) {
      int j = tid;
      if (j < 64) {
        bsel[j] = (double)bq[j];
      } else {
        int jj = j - 64;
        double s = (double)bku[jj];
        for (int l = 0; l < 512; ++l)
          s = fma((double)bkd[l], (double)Wku[(size_t)l * 1024 + jj], s);
        bsel[j] = s;
      }
    }
  } else {
    const int t = (id - 18433) * 4 + (tid >> 6);  // rope table remapped 64->256 thr
    const int i = tid & 63;
    int fi = (2 * i) & 63;
    double inv = pow(10000.0, -(double)fi / 64.0);
    double a = (double)t * inv;
    rc[t * 64 + i] = (float)cos(a);
    rs[t * 64 + i] = (float)sin(a);
  }
}

// ------------------------------------------------------------- device: fp64 selector GEMM slice
__device__ __forceinline__ void dev_sel_f64(char* smem, int bx, int by, int bz,
                                            const float* __restrict__ A,
                                            const double* __restrict__ Bsel,
                                            double* __restrict__ partial)
{
  double* Asd = (double*)smem;            // [32][33]
  double* Bsd = (double*)smem + 32 * 33;  // [32][66]
  const int m0 = bx * 32, n0 = by * 64;
  const int kbase = bz * 256, kend = kbase + 256;
  const int tid = threadIdx.x;
  const int tx = tid & 15, ty = tid >> 4;
  const int ar = tid >> 3, ac4 = (tid & 7) * 4;
  double acc[2][4] = {};

  f32x4 aN = *(const f32x4*)&A[(size_t)(m0 + ar) * 2048 + kbase + ac4];
  f64x2 bN[4];
  #pragma unroll
  for (int it = 0; it < 4; ++it) {
    int c = it * 256 + tid; int kk = c >> 5, n2 = (c & 31) * 2;
    bN[it] = *(const f64x2*)&Bsel[(size_t)(kbase + kk) * 128 + n0 + n2];
  }
  for (int k0 = kbase; k0 < kend; k0 += 32) {
    __syncthreads();
    Asd[ar * 33 + ac4] = (double)aN.x; Asd[ar * 33 + ac4 + 1] = (double)aN.y;
    Asd[ar * 33 + ac4 + 2] = (double)aN.z; Asd[ar * 33 + ac4 + 3] = (double)aN.w;
    #pragma unroll
    for (int it = 0; it < 4; ++it) {
      int c = it * 256 + tid; int kk = c >> 5, n2 = (c & 31) * 2;
      Bsd[kk * 66 + n2] = bN[it].x; Bsd[kk * 66 + n2 + 1] = bN[it].y;
    }
    __syncthreads();
    if (k0 + 32 < kend) {
      aN = *(const f32x4*)&A[(size_t)(m0 + ar) * 2048 + k0 + 32 + ac4];
      #pragma unroll
      for (int it = 0; it < 4; ++it) {
        int c = it * 256 + tid; int kk = c >> 5, n2 = (c & 31) * 2;
        bN[it] = *(const f64x2*)&Bsel[(size_t)(k0 + 32 + kk) * 128 + n0 + n2];
      }
    }
    #pragma unroll
    for (int kk = 0; kk < 32; ++kk) {
      double a0 = Asd[(ty * 2) * 33 + kk], a1 = Asd[(ty * 2 + 1) * 33 + kk];
      f64x2 b01 = *(const f64x2*)&Bsd[kk * 66 + tx * 2];
      f64x2 b23 = *(const f64x2*)&Bsd[kk * 66 + tx * 2 + 32];
      acc[0][0] = fma(a0, b01.x, acc[0][0]); acc[0][1] = fma(a0, b01.y, acc[0][1]);
      acc[0][2] = fma(a0, b23.x, acc[0][2]); acc[0][3] = fma(a0, b23.y, acc[0][3]);
      acc[1][0] = fma(a1, b01.x, acc[1][0]); acc[1][1] = fma(a1, b01.y, acc[1][1]);
      acc[1][2] = fma(a1, b23.x, acc[1][2]); acc[1][3] = fma(a1, b23.y, acc[1][3]);
    }
  }
  double* op = partial + (size_t)bz * 4096 * 128;
  #pragma unroll
  for (int i = 0; i < 2; ++i) {
    int row = m0 + ty * 2 + i;
    #pragma unroll
    for (int j = 0; j < 2; ++j) {
      op[(size_t)row * 128 + n0 + tx * 2 + j] = acc[i][j];
      op[(size_t)row * 128 + n0 + tx * 2 + 32 + j] = acc[i][j + 2];
    }
  }
}

// ------------------------------------------------------------- device: split-K reduce (8 slices)
__device__ __forceinline__ void dev_sel_reduce(int blk,
                                               const double* __restrict__ partial,
                                               const double* __restrict__ bias,
                                               double* __restrict__ qs64,
                                               double* __restrict__ ks64)
{
  const int idx = blk * 256 + threadIdx.x;
  const int row = idx >> 7, n = idx & 127;
  const size_t S = 4096 * 128;
  double v = partial[idx];
  #pragma unroll
  for (int z = 1; z < 8; ++z) v += partial[(size_t)z * S + idx];  // fixed order
  v += bias[n];
  if (n < 64) qs64[(size_t)row * 64 + n] = v;
  else        ks64[(size_t)row * 64 + (n - 64)] = v;
}

// ------------------------------------------------------------- fp64 transpose
__global__ __launch_bounds__(256) void k_transpose64(const double* __restrict__ in,
                                                     double* __restrict__ out)
{
  __shared__ double tile[32][33];
  const int bt = blockIdx.z;
  const int c0 = blockIdx.x * 32;
  const int r0 = blockIdx.y * 32;
  int tx = threadIdx.x & 31, ty = threadIdx.x >> 5;
  const double* ip = in + (size_t)bt * 2048 * 64;
  double* op = out + (size_t)bt * 64 * 2048;
  #pragma unroll
  for (int i = ty; i < 32; i += 8) tile[i][tx] = ip[(size_t)(r0 + i) * 64 + c0 + tx];
  __syncthreads();
  #pragma unroll
  for (int i = ty; i < 32; i += 8) op[(size_t)(c0 + i) * 2048 + r0 + tx] = tile[tx][i];
}

// ------------------------------------------------------------- device: score (16-row tiles)
// su keys as tiled fp64 GEMM; 16 rows x 512 keys, K=64; 32 fp64 acc/thread (static).
__device__ __forceinline__ void dev_score(char* smem, int sc,
                                          const double* __restrict__ qs,
                                          const double* __restrict__ ksT,
                                          u64* __restrict__ su)
{
  const int rt = sc >> 2;               // 16-row tile, 0..255
  const int kc = sc & 3;                // 512-key chunk
  const int tmax = ((rt & 127) << 4) + 15;
  if (kc * 512 > tmax) return;          // fully-causal chunk
  const int b = rt >> 7;
  const int tid = threadIdx.x;
  double* As = (double*)smem;           // [16][64]
  {
    const double* qp = qs + (size_t)rt * 16 * 64;
    #pragma unroll
    for (int i = 0; i < 4; ++i) As[tid * 4 + i] = qp[tid * 4 + i];
  }
  __syncthreads();
  const int k0 = kc * 512 + tid;
  const int k1 = k0 + 256;
  const double* kb = ksT + (size_t)b * 64 * 2048;
  double acc0[16] = {}, acc1[16] = {};
  for (int d = 0; d < 64; ++d) {
    const double b0 = kb[(size_t)d * 2048 + k0];
    const double b1 = kb[(size_t)d * 2048 + k1];
    #pragma unroll
    for (int r = 0; r < 16; ++r) {
      const double a = As[r * 64 + d];  // block-uniform broadcast
      acc0[r] = fma(a, b0, acc0[r]);
      acc1[r] = fma(a, b1, acc1[r]);
    }
  }
  #pragma unroll
  for (int r = 0; r < 16; ++r) {
    const int row = rt * 16 + r;
    u64 u0 = (u64)__double_as_longlong(acc0[r]);
    u0 = (u0 >> 63) ? ~u0 : (u0 | 0x8000000000000000ull);
    su[(size_t)row * 2048 + k0] = u0;
    u64 u1 = (u64)__double_as_longlong(acc1[r]);
    u1 = (u1 >> 63) ? ~u1 : (u1 | 0x8000000000000000ull);
    su[(size_t)row * 2048 + k1] = u1;
  }
}

// ------------------------------------------------------------- device: fp16 MFMA GEMM
// Tile 128(M) x 64(N), BK=64, 4 waves, acc[4][2]. (Proven R14-R18.)
template <int MODE>
__device__ __forceinline__ void dev_gemm_bt(char* smem, int gbx, int gby, int nbx, int nby,
                                            const f16* __restrict__ A,
                                            const f16* __restrict__ BT,
                                            const float* __restrict__ bias,
                                            float* __restrict__ C, f16* __restrict__ Ch,
                                            f16* __restrict__ Kout, f16* __restrict__ Vout,
                                            const float* __restrict__ rc,
                                            const float* __restrict__ rs,
                                            int K, int lda, int ldb, int ldc)
{
  f16* As = (f16*)smem;             // 128*64
  f16* Bs = (f16*)smem + 128 * 64;  // 64*64
  const int tid = threadIdx.x;
  const int lane = tid & 63;
  const int wave = tid >> 6;
  int bx = gbx, by = gby;
  {
    const int nwg = nbx * nby;
    if ((nwg & 7) == 0) {
      const int bid = by * nbx + bx;
      const int cpx = nwg >> 3;
      const int sbid = (bid & 7) * cpx + (bid >> 3);
      bx = sbid % nbx;
      by = sbid / nbx;
    }
  }
  const int m0 = bx * 128, n0 = by * 64;
  const int wr = (wave >> 1) * 64, wc = (wave & 1) * 32;
  const int lrow = lane & 15;
  const int kgrp = (lane >> 4) * 8;
  f32x4 acc[4][2] = {};

  for (int k0 = 0; k0 < K; k0 += 64) {
    __syncthreads();
    #pragma unroll
    for (int it = 0; it < 4; ++it) {  // A: 128x64
      int c = it * 256 + tid;
      int r = c >> 3, c8 = (c & 7) * 8;
      int lbase = (it * 256 + (tid & 192)) * 8;
      const f16* ga = A + (size_t)(m0 + r) * lda + k0 + c8;
      __builtin_amdgcn_global_load_lds((const __attribute__((address_space(1))) u32*)ga,
                                       (__attribute__((address_space(3))) u32*)&As[lbase],
                                       16, 0, 0);
    }
    #pragma unroll
    for (int it = 0; it < 2; ++it) {  // B: 64x64
      int c = it * 256 + tid;
      int r = c >> 3, c8 = (c & 7) * 8;
      int lbase = (it * 256 + (tid & 192)) * 8;
      const f16* gb = BT + (size_t)(n0 + r) * ldb + k0 + c8;
      __builtin_amdgcn_global_load_lds((const __attribute__((address_space(1))) u32*)gb,
                                       (__attribute__((address_space(3))) u32*)&Bs[lbase],
                                       16, 0, 0);
    }
    __syncthreads();
    #pragma unroll
    for (int ks = 0; ks < 2; ++ks) {
      f16x8 af[4], bfr[2];
      #pragma unroll
      for (int m = 0; m < 4; ++m)
        af[m] = *(const f16x8*)&As[(wr + m * 16 + lrow) * 64 + ks * 32 + kgrp];
      #pragma unroll
      for (int n = 0; n < 2; ++n)
        bfr[n] = *(const f16x8*)&Bs[(wc + n * 16 + lrow) * 64 + ks * 32 + kgrp];
      #pragma unroll
      for (int m = 0; m < 4; ++m)
        #pragma unroll
        for (int n = 0; n < 2; ++n)
          acc[m][n] = __builtin_amdgcn_mfma_f32_16x16x32_f16(af[m], bfr[n], acc[m][n], 0, 0, 0);
    }
  }
  const int rbase = m0 + wr + (lane >> 4) * 4;  // C/D: col=lane&15, row=(lane>>4)*4+reg [m89]
  #pragma unroll
  for (int n = 0; n < 2; ++n) {
    int col = n0 + wc + n * 16 + lrow;
    float bv = bias ? bias[col] : 0.0f;
    const int ri = (col & 127) >> 1;  // rope pair index (MODE 2/3)
    #pragma unroll
    for (int m = 0; m < 4; ++m) {
      #pragma unroll
      for (int j = 0; j < 4; ++j) {
        int rowi = rbase + m * 16 + j;
        float v = acc[m][n][j] + bv;
        if (MODE == 0) {
          C[(size_t)rowi * ldc + col] = v;
        } else if (MODE == 1) {
          Ch[(size_t)rowi * ldc + col] = (f16)v;
        } else if (MODE == 2) {
          float vp = __shfl_xor(v, 1);
          int t = rowi & 2047;
          float c_ = rc[t * 64 + ri], s_ = rs[t * 64 + ri];
          float r_ = (lrow & 1) ? (vp * s_ + v * c_) : (v * c_ - vp * s_);
          Ch[(size_t)rowi * ldc + col] = (f16)r_;
        } else {  // MODE 3
          float vp = __shfl_xor(v, 1);
          if (n0 < 512) {
            int t = rowi & 2047;
            float c_ = rc[t * 64 + ri], s_ = rs[t * 64 + ri];
            float r_ = (lrow & 1) ? (vp * s_ + v * c_) : (v * c_ - vp * s_);
            Kout[(size_t)rowi * 512 + col] = (f16)r_;
          } else {
            Vout[(size_t)rowi * 512 + (col - 512)] = (f16)v;
          }
        }
      }
    }
  }
}

// ---------------------------------------------------------------- launch wrappers
// fusedA: sel_f64 splitK=8 (2048 blocks, fp64 VALU) || Wkd GEMM (256 blocks, MFMA)
__global__ __launch_bounds__(256) void k_fusedA(const float* __restrict__ x,
                                                const double* __restrict__ Bsel,
                                                double* __restrict__ partial,
                                                const f16* __restrict__ xh,
                                                const f16* __restrict__ WkdT,
                                                const float* __restrict__ bkd,
                                                f16* __restrict__ cbf)
{
  __shared__ __align__(16) char smem[25600];
  const int id = blockIdx.x;
  if (id < 2048) {
    dev_sel_f64(smem, id & 127, (id >> 7) & 1, id >> 8, x, Bsel, partial);
  } else {
    const int g = id - 2048;
    dev_gemm_bt<1>(smem, g & 31, g >> 5, 32, 8, xh, WkdT, bkd, nullptr, cbf,
                   nullptr, nullptr, nullptr, nullptr, 2048, 2048, 2048, 512);
  }
}

// fusedC: Wku GEMM (512 blocks) || sel_reduce (2048 blocks)
__global__ __launch_bounds__(256) void k_fusedC(const f16* __restrict__ cbf,
                                                const f16* __restrict__ WkuT,
                                                const float* __restrict__ bku,
                                                f16* __restrict__ krope, f16* __restrict__ vbf,
                                                const float* __restrict__ rc,
                                                const float* __restrict__ rs,
                                                const double* __restrict__ partial,
                                                const double* __restrict__ bsel,
                                                double* __restrict__ qs64,
                                                double* __restrict__ ks64)
{
  __shared__ __align__(16) char smem[24576];
  const int id = blockIdx.x;
  if (id < 512) {
    dev_gemm_bt<3>(smem, id & 31, id >> 5, 32, 16, cbf, WkuT, bku, nullptr, nullptr,
                   krope, vbf, rc, rs, 512, 512, 512, 1024);
  } else {
    dev_sel_reduce(id - 512, partial, bsel, qs64, ks64);
  }
}

// fusedQS: Wq GEMM MODE2 (1024 blocks, MFMA) || score (1024 blocks, fp64 VALU)
// (mirrors fusedA's proven MFMA||fp64 pattern; R13's failed fusion mixed huge
// streaming reads — score only writes 64MB, reads 4MB)
__global__ __launch_bounds__(256) void k_fusedQS(const f16* __restrict__ xh,
                                                 const f16* __restrict__ WqT,
                                                 const float* __restrict__ bq,
                                                 f16* __restrict__ qrope,
                                                 const float* __restrict__ rc,
                                                 const float* __restrict__ rs,
                                                 const double* __restrict__ qs64,
                                                 const double* __restrict__ ksT,
                                                 u64* __restrict__ gsu)
{
  __shared__ __align__(16) char smem[24576];
  const int id = blockIdx.x;
  if (id < 1024) {
    dev_gemm_bt<2>(smem, id & 31, id >> 5, 32, 32, xh, WqT, bq, nullptr, qrope,
                   nullptr, nullptr, rc, rs, 2048, 2048, 2048, 2048);
  } else {
    dev_score(smem, id - 1024, qs64, ksT, gsu);
  }
}

// Wo GEMM standalone (MODE 0, grid 32x32)
__global__ __launch_bounds__(256) void k_gemmO(const f16* __restrict__ A,
                                               const f16* __restrict__ BT,
                                               const float* __restrict__ bias,
                                               float* __restrict__ C)
{
  __shared__ __align__(16) char smem[24576];
  dev_gemm_bt<0>(smem, blockIdx.x, blockIdx.y, 32, 32, A, BT, bias, C, nullptr,
                 nullptr, nullptr, nullptr, nullptr, 2048, 2048, 2048, 2048);
}

// ------------------------------------------------------------- k_select: exact top-64
// 1 row/block, 256 threads (18.7KB LDS -> 8 blocks/CU; halves per-block serial
// phases vs 2-row). Proven machinery: register key cache (E=8), wave-uniform hist
// aggregation, shfl scans + 4-wave combine, deterministic position-computed emit.
__global__ __launch_bounds__(256) void k_select(const u64* __restrict__ gsu,
                                                int* __restrict__ selcnt,
                                                int* __restrict__ selidx)
{
  const int row = blockIdx.x;
  const int t = row & 2047;
  const int tid = threadIdx.x;
  const int lane = tid & 63, wave = tid >> 6;
  int* outp = selidx + (size_t)row * 68;
  if (t < 64) {
    for (int jj = tid; jj <= t; jj += 256) outp[jj] = jj;
    if (tid == 0) selcnt[row] = t + 1;
    return;
  }
  __shared__ u64 su[2048];
  __shared__ unsigned hist[256];
  __shared__ unsigned wsum[4];
  __shared__ unsigned s_bsel, s_larger, s_cnt;
  __shared__ u64 s_thr;
  __shared__ int s_remfin;
  __shared__ int cand[128];
  __shared__ u64 ckey[128];

  {
    const u64* g = gsu + (size_t)row * 2048;
    for (int jj = tid; jj <= t; jj += 256) su[suX(jj)] = g[jj];
  }
  __syncthreads();

  const int c0 = tid * 8;
  u64 kv[8]; bool kvv[8];
  #pragma unroll
  for (int e = 0; e < 8; ++e) {
    const int jj = c0 + e;
    kvv[e] = (jj <= t);
    kv[e] = kvv[e] ? su[suX(jj)] : 0;
  }

  u64 prefix = 0;
  int remaining = 64;
  int broke = 0, sh_final = 0;
  for (int byte = 7; byte >= 0; --byte) {
    const int sh = byte * 8;
    hist[tid] = 0;
    __syncthreads();
    {
      unsigned bn[8]; bool vl[8];
      #pragma unroll
      for (int e = 0; e < 8; ++e) {
        vl[e] = kvv[e] && ((byte == 7) || (((kv[e] ^ prefix) >> (sh + 8)) == 0));
        bn[e] = (unsigned)((kv[e] >> sh) & 255);
      }
      unsigned myBin = 0xFFFFFFFFu, cntLoc = 0;
      bool localSame = true;
      #pragma unroll
      for (int e = 0; e < 8; ++e) {
        if (vl[e]) {
          if (myBin == 0xFFFFFFFFu) myBin = bn[e];
          else if (bn[e] != myBin) localSame = false;
          ++cntLoc;
        }
      }
      const bool hasValid = (cntLoc > 0);
      unsigned vmin = hasValid ? myBin : 0xFFFFFFFFu;
      unsigned vmax = hasValid ? myBin : 0u;
      unsigned csum = cntLoc;
      #pragma unroll
      for (int off = 32; off; off >>= 1) {
        unsigned a = __shfl_xor(vmin, off); vmin = a < vmin ? a : vmin;
        unsigned bmx = __shfl_xor(vmax, off); vmax = bmx > vmax ? bmx : vmax;
        csum += __shfl_xor(csum, off);
      }
      const bool anyMixed = (__ballot(hasValid && !localSame) != 0ull);
      const bool anyValid = (__ballot(hasValid) != 0ull);
      if (!anyMixed && anyValid && vmin == vmax) {
        if (lane == 0) atomicAdd(&hist[vmin], csum);  // one atomic per wave
      } else if (hasValid) {
        #pragma unroll
        for (int e = 0; e < 8; ++e) {
          if (vl[e]) {
            bool first = true;
            #pragma unroll
            for (int p = 0; p < 8; ++p)
              if (p < e && vl[p] && bn[p] == bn[e]) first = false;
            if (first) {
              unsigned c = 0;
              #pragma unroll
              for (int q = 0; q < 8; ++q)
                if (q >= e && vl[q] && bn[q] == bn[e]) ++c;
              atomicAdd(&hist[bn[e]], c);
            }
          }
        }
      }
    }
    __syncthreads();
    // suffix-inclusive scan of hist (4 waves)
    const unsigned h = hist[tid];
    unsigned v = h;
    #pragma unroll
    for (int off = 1; off < 64; off <<= 1) {
      unsigned tv = __shfl_down(v, off);
      if (lane + off < 64) v += tv;
    }
    if (lane == 0) wsum[wave] = v;
    __syncthreads();
    unsigned add = 0;
    #pragma unroll
    for (int w = 0; w < 4; ++w)
      if (w > wave) add += wsum[w];
    const unsigned inc = v + add;
    const unsigned cumAbove = inc - h;
    __syncthreads();  // wsum reusable
    if ((int)cumAbove < remaining && (int)inc >= remaining) {
      s_bsel = (unsigned)tid;
      s_larger = cumAbove;
      s_cnt = inc - cumAbove;
    }
    __syncthreads();
    prefix |= ((u64)s_bsel << sh);
    remaining -= (int)s_larger;
    int cnt = (int)s_cnt;
    if (cnt <= 128) { broke = 1; sh_final = sh; break; }
  }
  u64 thr;
  int remfin;
  if (broke) {
    unsigned cg = 0;
    #pragma unroll
    for (int e = 0; e < 8; ++e)
      if (kvv[e] && (((kv[e] ^ prefix) >> sh_final) == 0)) ++cg;
    unsigned v = cg;
    #pragma unroll
    for (int off = 1; off < 64; off <<= 1) {
      unsigned tv = __shfl_up(v, off);
      if (lane >= off) v += tv;
    }
    __syncthreads();
    if (lane == 63) wsum[wave] = v;
    __syncthreads();
    unsigned add = 0, tot = 0;
    #pragma unroll
    for (int w = 0; w < 4; ++w) {
      tot += wsum[w];
      if (w < wave) add += wsum[w];
    }
    const int C = (int)tot;
    int pos = (int)(v + add - cg);
    __syncthreads();
    #pragma unroll
    for (int e = 0; e < 8; ++e)
      if (kvv[e] && (((kv[e] ^ prefix) >> sh_final) == 0)) cand[pos++] = c0 + e;
    __syncthreads();
    if (tid < C) ckey[tid] = su[suX(cand[tid])];
    __syncthreads();
    if (tid < C) {
      u64 k = ckey[tid];
      int g = 0, eq = 0;
      for (int j = 0; j < C; ++j) {
        g += (ckey[j] > k) ? 1 : 0;
        eq += (ckey[j] == k) ? 1 : 0;
      }
      if (g < remaining && remaining <= g + eq) {
        s_thr = k;
        s_remfin = remaining - g;
      }
    }
    __syncthreads();
    thr = s_thr;
    remfin = s_remfin;
  } else {
    thr = prefix;
    remfin = remaining;
  }
  __syncthreads();
  // ---- deterministic emit: diag, greaters asc, first remfin ties asc ----
  unsigned cg = 0, ct_ = 0;
  #pragma unroll
  for (int e = 0; e < 8; ++e) {
    if (kvv[e]) {
      cg += (kv[e] > thr) ? 1u : 0u;
      ct_ += (kv[e] == thr) ? 1u : 0u;
    }
  }
  const unsigned pack = cg | (ct_ << 16);
  {
    unsigned v = pack;
    #pragma unroll
    for (int off = 1; off < 64; off <<= 1) {
      unsigned tv = __shfl_up(v, off);
      if (lane >= off) v += tv;
    }
    if (lane == 63) wsum[wave] = v;
    __syncthreads();
    unsigned add = 0, tot = 0;
    #pragma unroll
    for (int w = 0; w < 4; ++w) {
      tot += wsum[w];
      if (w < wave) add += wsum[w];
    }
    const unsigned excl = v + add - pack;
    __syncthreads();
    const unsigned Gtot = tot & 0xFFFFu;
    const u64 ut = su[suX(t)];
    const unsigned gt = (ut > thr) ? 1u : 0u;
    const unsigned tt = (ut == thr) ? 1u : 0u;
    const int GtotX = (int)(Gtot - gt);
    int gpos = (int)(excl & 0xFFFFu);
    int tpos = (int)(excl >> 16);
    #pragma unroll
    for (int e = 0; e < 8; ++e) {
      const int jj = c0 + e;
      if (!kvv[e]) break;
      if (kv[e] > thr) {
        if (jj != t) outp[1 + gpos] = jj;
        ++gpos;
      } else if (kv[e] == thr) {
        if (jj != t && tpos < remfin) outp[1 + GtotX + tpos] = jj;
        ++tpos;
      }
    }
    if (tid == 0) {
      outp[0] = t;
      const unsigned Ttot = tot >> 16;
      int tb = (int)(Ttot - tt);
      int emitT = tb < remfin ? tb : remfin;
      selcnt[row] = 1 + GtotX + emitT;  // 64 or 65
    }
  }
}

// ------------------------------------------------------------- sparse attention
// R18 structure; Q held in registers (broadcast loads) instead of qlds -> drops
// staging + 16 LDS reads per dot; values and fdot2 order identical.
__global__ __launch_bounds__(256) void k_attn(const f16* __restrict__ qr,
                                              const f16* __restrict__ kr,
                                              const f16* __restrict__ vv,
                                              const int* __restrict__ selcnt,
                                              const int* __restrict__ selidx,
                                              f16* __restrict__ y)
{
  const int blk = blockIdx.x;  // row*4 + kvh
  const int row = blk >> 2, kvh = blk & 3;
  const int b = row >> 11;
  const int tid = threadIdx.x, lane = tid & 63, wave = tid >> 6;
  const int cnt = selcnt[row];
  __shared__ int sidx[68];
  __shared__ __align__(16) f16 Kl[65 * 128];   // chunk-XOR swizzled
  __shared__ __align__(16) f16 Vl[68 * 128];   // linear, rows [cnt,68) zeroed
  __shared__ __align__(4) f16 ph[4][72];       // P in f16, [cnt..72) zeroed
  if (tid < cnt) sidx[tid] = selidx[(size_t)row * 68 + tid];
  // Q in registers (wave-uniform addresses -> broadcast loads)
  const f16* qb = qr + ((size_t)row * 16 + kvh * 4 + wave) * 128;
  f16x8 qf[16];
  #pragma unroll
  for (int i = 0; i < 16; ++i) qf[i] = *(const f16x8*)&qb[i * 8];
  __syncthreads();  // sidx ready

  f16x8 kreg[5], vreg[5];
  int rr[5], cc[5]; bool vld[5];
  #pragma unroll
  for (int it = 0; it < 5; ++it) {
    const int c = it * 256 + tid;
    const int r = c >> 4, ch = c & 15;
    const bool ok = (r < cnt);
    const int rsafe = ok ? sidx[r] : sidx[0];
    const size_t kbase = ((size_t)(b * 2048 + rsafe)) * 512 + kvh * 128 + ch * 8;
    kreg[it] = *(const f16x8*)&kr[kbase];
    vreg[it] = *(const f16x8*)&vv[kbase];
    rr[it] = r; cc[it] = ch; vld[it] = ok;
  }
  #pragma unroll
  for (int it = 0; it < 5; ++it) {
    if (vld[it]) {
      *(f16x8*)&Kl[rr[it] * 128 + ((cc[it] ^ (rr[it] & 15)) * 8)] = kreg[it];
      *(f16x8*)&Vl[rr[it] * 128 + cc[it] * 8] = vreg[it];
    }
  }
  for (int i = tid; i < (68 - cnt) * 64; i += 256)
    ((u32*)Vl)[cnt * 64 + i] = 0u;
  __syncthreads();

  const float SCALE = 0.08838834764831845f;  // 1/sqrt(128)
  auto dotk = [&](int r) -> float {
    const int sw = r & 15;
    float s = 0.0f;
    #pragma unroll
    for (int i = 0; i < 16; ++i) {
      f16x8 k8 = *(const f16x8*)&Kl[r * 128 + ((i ^ sw) * 8)];
      f16x8 q8 = qf[i];
      #pragma unroll
      for (int e = 0; e < 4; ++e) {
        f16x2 ka; ka.x = k8[2 * e]; ka.y = k8[2 * e + 1];
        f16x2 qa; qa.x = q8[2 * e]; qa.y = q8[2 * e + 1];
        s = __builtin_amdgcn_fdot2(ka, qa, s, false);
      }
    }
    return s * SCALE;
  };

  float s1 = -__builtin_inff(), s2 = -__builtin_inff();
  if (lane < cnt) s1 = dotk(lane);
  if (lane + 64 < cnt) s2 = dotk(lane + 64);  // only lane 0, cnt==65
  float mx = fmaxf(s1, s2);
  #pragma unroll
  for (int off = 32; off; off >>= 1) mx = fmaxf(mx, __shfl_xor(mx, off));
  float p1 = (lane < cnt) ? __expf(s1 - mx) : 0.0f;
  float p2 = (lane + 64 < cnt) ? __expf(s2 - mx) : 0.0f;
  float l = p1 + p2;
  #pragma unroll
  for (int off = 32; off; off >>= 1) l += __shfl_xor(l, off);
  float linv = 1.0f / l;
  ph[wave][lane] = (f16)p1;
  if (lane == 0) ph[wave][64] = (f16)p2;
  if (lane >= 1 && lane < 8) ph[wave][64 + lane] = (f16)0.f;
  __syncthreads();

  float y0 = 0.0f, y1 = 0.0f;
  const int d2 = lane * 2;
  for (int j = 0; j < cnt; j += 2) {
    f16x2 pp = *(const f16x2*)&ph[wave][j];
    f16x2 va = *(const f16x2*)&Vl[(j + 0) * 128 + d2];
    f16x2 vb = *(const f16x2*)&Vl[(j + 1) * 128 + d2];
    f16x2 v0; v0.x = va.x; v0.y = vb.x;
    f16x2 v1; v1.x = va.y; v1.y = vb.y;
    y0 = __builtin_amdgcn_fdot2(pp, v0, y0, false);
    y1 = __builtin_amdgcn_fdot2(pp, v1, y1, false);
  }
  y0 *= linv; y1 *= linv;
  f16x2 o; o.x = (f16)y0; o.y = (f16)y1;
  *(f16x2*)&y[(size_t)row * 2048 + (kvh * 4 + wave) * 128 + d2] = o;
}

// ================================================================ launch
extern "C" void kernel_launch(void* const* d_in, const int* in_sizes, int n_in,
                              void* d_out, int out_size, void* d_ws, size_t ws_size,
                              hipStream_t stream)
{
  (void)in_sizes; (void)n_in; (void)out_size; (void)ws_size;
  const float* x   = (const float*)d_in[0];
  const float* Wq  = (const float*)d_in[1];
  const float* bq  = (const float*)d_in[2];
  const float* Wkd = (const float*)d_in[3];
  const float* bkd = (const float*)d_in[4];
  const float* Wku = (const float*)d_in[5];
  const float* bku = (const float*)d_in[6];
  const float* Wo  = (const float*)d_in[7];
  const float* bo  = (const float*)d_in[8];
  float* out = (float*)d_out;

  char* ws = (char*)d_ws;
  size_t o = 0;
  auto alloc = [&](size_t bytes) -> void* {
    o = (o + 255) & ~(size_t)255;
    void* p = ws + o;
    o += bytes;
    return p;
  };
  f16* WqT   = (f16*)alloc(2048ull * 2048 * 2);
  f16* WoT   = (f16*)alloc(2048ull * 2048 * 2);
  f16* WkdT  = (f16*)alloc(512ull * 2048 * 2);
  f16* WkuT  = (f16*)alloc(1024ull * 512 * 2);
  f16* xh    = (f16*)alloc(4096ull * 2048 * 2);
  f16* yh    = (f16*)alloc(4096ull * 2048 * 2);  // attention output
  f16* cbf   = (f16*)alloc(4096ull * 512 * 2);
  float* rc  = (float*)alloc(2048ull * 64 * 4);
  float* rs  = (float*)alloc(2048ull * 64 * 4);
  f16* qrope = (f16*)alloc(4096ull * 2048 * 2);
  f16* krope = (f16*)alloc(4096ull * 512 * 2);
  f16* vbf   = (f16*)alloc(4096ull * 512 * 2);
  int* selcnt = (int*)alloc(4096ull * 4);
  int* selidx = (int*)alloc(4096ull * 68 * 4);
  double* Bsel = (double*)alloc(2048ull * 128 * 8);
  double* bsel = (double*)alloc(128 * 8);
  double* qs64 = (double*)alloc(4096ull * 64 * 8);
  double* ks64 = (double*)alloc(4096ull * 64 * 8);
  double* ksT  = (double*)alloc(2ull * 64 * 2048 * 8);
  double* partial = (double*)alloc(8ull * 4096 * 128 * 8);  // 32 MiB (split-K=8)
  u64* gsu = (u64*)alloc(4096ull * 2048 * 8);               // 64 MiB score keys

  // --- megaP: all prep (transposes, cast, Bsel, bsel, rope tables) in one launch ---
  k_megaP<<<18945, 256, 0, stream>>>(Wq, WqT, Wkd, WkdT, Wku, WkuT, Wo, WoT, x, xh,
                                     Bsel, bq, bkd, bku, bsel, rc, rs);

  // --- fusedA: fp64 selector GEMM (split-K=8) || Wkd GEMM ---
  k_fusedA<<<2304, 256, 0, stream>>>(x, Bsel, partial, xh, WkdT, bkd, cbf);

  // --- fusedC: Wku GEMM (rope-k/V fused) || split-K reduce ---
  k_fusedC<<<2560, 256, 0, stream>>>(cbf, WkuT, bku, krope, vbf, rc, rs,
                                     partial, bsel, qs64, ks64);

  // --- ksT for coalesced score reads ---
  k_transpose64<<<dim3(2, 64, 2), 256, 0, stream>>>(ks64, ksT);

  // --- fusedQS: Wq GEMM (rope-q fused) || score keys ---
  k_fusedQS<<<2048, 256, 0, stream>>>(xh, WqT, bq, qrope, rc, rs, qs64, ksT, gsu);

  // --- select (1 row/block) ---
  k_select<<<4096, 256, 0, stream>>>(gsu, selcnt, selidx);

  // --- sparse attention (Q in registers) ---
  k_attn<<<16384, 256, 0, stream>>>(qrope, krope, vbf, selcnt, selidx, yh);

  // --- output projection ---
  k_gemmO<<<dim3(32, 32), 256, 0, stream>>>(yh, WoT, bo, out);
}

// Round 20
// 480.939 us; speedup vs baseline: 1.0239x; 1.0006x over previous
//
#include <hip/hip_runtime.h>

typedef unsigned int u32;
typedef unsigned long long u64;
typedef _Float16 f16;
typedef __attribute__((ext_vector_type(2))) _Float16 f16x2;
typedef __attribute__((ext_vector_type(4))) _Float16 f16x4;
typedef __attribute__((ext_vector_type(8))) _Float16 f16x8;
typedef __attribute__((ext_vector_type(4))) float f32x4;
typedef __attribute__((ext_vector_type(2))) double f64x2;

// Problem constants: B=2, T=2048, D=2048, LAT=512, H=16, HD=128, NKV=4, G=4,
// SEL_DIM=64, TOPK=64, NROW = 4096

// ---------------------------------------------------------------- device: transpose+cast
__device__ __forceinline__ void dev_transpose_cast(char* smem, int bx, int by,
                                                   const float* __restrict__ in,
                                                   f16* __restrict__ out, int R, int C)
{
  float* tile = (float*)smem;  // [32][33]
  int c0 = bx * 32, r0 = by * 32;
  int tx = threadIdx.x & 31, ty = threadIdx.x >> 5;
  #pragma unroll
  for (int i = ty; i < 32; i += 8) tile[i * 33 + tx] = in[(size_t)(r0 + i) * C + c0 + tx];
  __syncthreads();
  #pragma unroll
  for (int i = ty; i < 32; i += 8) out[(size_t)(c0 + i) * R + r0 + tx] = (f16)tile[tx * 33 + i];
}

// ---------------------------------------------------------------- megaP: ALL prep in one launch
__global__ __launch_bounds__(256) void k_megaP(const float* __restrict__ Wq, f16* __restrict__ WqT,
                                               const float* __restrict__ Wkd, f16* __restrict__ WkdT,
                                               const float* __restrict__ Wku, f16* __restrict__ WkuT,
                                               const float* __restrict__ Wo, f16* __restrict__ WoT,
                                               const float* __restrict__ x, f16* __restrict__ xh,
                                               double* __restrict__ Bsel,
                                               const float* __restrict__ bq,
                                               const float* __restrict__ bkd,
                                               const float* __restrict__ bku,
                                               double* __restrict__ bsel,
                                               float* __restrict__ rc, float* __restrict__ rs)
{
  __shared__ __align__(16) char smem[4224];
  const int id = blockIdx.x;
  const int tid = threadIdx.x;
  if (id < 4096) {
    dev_transpose_cast(smem, id & 63, id >> 6, Wq, WqT, 2048, 2048);
  } else if (id < 5120) {
    int g = id - 4096;
    dev_transpose_cast(smem, g & 15, g >> 4, Wkd, WkdT, 2048, 512);
  } else if (id < 5632) {
    int g = id - 5120;
    dev_transpose_cast(smem, g & 31, g >> 5, Wku, WkuT, 512, 1024);
  } else if (id < 9728) {
    int g = id - 5632;
    dev_transpose_cast(smem, g & 63, g >> 6, Wo, WoT, 2048, 2048);
  } else if (id < 17920) {
    int i = (id - 9728) * 256 + tid;
    f32x4 v = *(const f32x4*)&x[(size_t)i * 4];
    f16x4 h; h.x = (f16)v.x; h.y = (f16)v.y; h.z = (f16)v.z; h.w = (f16)v.w;
    *(f16x4*)&xh[(size_t)i * 4] = h;
  } else if (id < 18432) {
    const int k = (id - 17920) * 4 + (tid >> 6);  // prep_sel remapped 64->256 thr
    const int j = tid & 63;
    Bsel[(size_t)k * 128 + j] = (double)Wq[(size_t)k * 2048 + j];
    double s = 0.0;
    for (int l = 0; l < 512; ++l)
      s = fma((double)Wkd[(size_t)k * 512 + l], (double)Wku[(size_t)l * 1024 + j], s);
    Bsel[(size_t)k * 128 + 64 + j] = s;
  } else if (id == 18432) {
    if (tid < 128) {
      int j = tid;
      if (j < 64) {
        bsel[j] = (double)bq[j];
      } else {
        int jj = j - 64;
        double s = (double)bku[jj];
        for (int l = 0; l < 512; ++l)
          s = fma((double)bkd[l], (double)Wku[(size_t)l * 1024 + jj], s);
        bsel[j] = s;
      }
    }
  } else {
    const int t = (id - 18433) * 4 + (tid >> 6);  // rope table remapped 64->256 thr
    const int i = tid & 63;
    int fi = (2 * i) & 63;
    double inv = pow(10000.0, -(double)fi / 64.0);
    double a = (double)t * inv;
    rc[t * 64 + i] = (float)cos(a);
    rs[t * 64 + i] = (float)sin(a);
  }
}

// ------------------------------------------------------------- device: fp64 selector GEMM slice
__device__ __forceinline__ void dev_sel_f64(char* smem, int bx, int by, int bz,
                                            const float* __restrict__ A,
                                            const double* __restrict__ Bsel,
                                            double* __restrict__ partial)
{
  double* Asd = (double*)smem;            // [32][33]
  double* Bsd = (double*)smem + 32 * 33;  // [32][66]
  const int m0 = bx * 32, n0 = by * 64;
  const int kbase = bz * 256, kend = kbase + 256;
  const int tid = threadIdx.x;
  const int tx = tid & 15, ty = tid >> 4;
  const int ar = tid >> 3, ac4 = (tid & 7) * 4;
  double acc[2][4] = {};

  f32x4 aN = *(const f32x4*)&A[(size_t)(m0 + ar) * 2048 + kbase + ac4];
  f64x2 bN[4];
  #pragma unroll
  for (int it = 0; it < 4; ++it) {
    int c = it * 256 + tid; int kk = c >> 5, n2 = (c & 31) * 2;
    bN[it] = *(const f64x2*)&Bsel[(size_t)(kbase + kk) * 128 + n0 + n2];
  }
  for (int k0 = kbase; k0 < kend; k0 += 32) {
    __syncthreads();
    Asd[ar * 33 + ac4] = (double)aN.x; Asd[ar * 33 + ac4 + 1] = (double)aN.y;
    Asd[ar * 33 + ac4 + 2] = (double)aN.z; Asd[ar * 33 + ac4 + 3] = (double)aN.w;
    #pragma unroll
    for (int it = 0; it < 4; ++it) {
      int c = it * 256 + tid; int kk = c >> 5, n2 = (c & 31) * 2;
      Bsd[kk * 66 + n2] = bN[it].x; Bsd[kk * 66 + n2 + 1] = bN[it].y;
    }
    __syncthreads();
    if (k0 + 32 < kend) {
      aN = *(const f32x4*)&A[(size_t)(m0 + ar) * 2048 + k0 + 32 + ac4];
      #pragma unroll
      for (int it = 0; it < 4; ++it) {
        int c = it * 256 + tid; int kk = c >> 5, n2 = (c & 31) * 2;
        bN[it] = *(const f64x2*)&Bsel[(size_t)(k0 + 32 + kk) * 128 + n0 + n2];
      }
    }
    #pragma unroll
    for (int kk = 0; kk < 32; ++kk) {
      double a0 = Asd[(ty * 2) * 33 + kk], a1 = Asd[(ty * 2 + 1) * 33 + kk];
      f64x2 b01 = *(const f64x2*)&Bsd[kk * 66 + tx * 2];
      f64x2 b23 = *(const f64x2*)&Bsd[kk * 66 + tx * 2 + 32];
      acc[0][0] = fma(a0, b01.x, acc[0][0]); acc[0][1] = fma(a0, b01.y, acc[0][1]);
      acc[0][2] = fma(a0, b23.x, acc[0][2]); acc[0][3] = fma(a0, b23.y, acc[0][3]);
      acc[1][0] = fma(a1, b01.x, acc[1][0]); acc[1][1] = fma(a1, b01.y, acc[1][1]);
      acc[1][2] = fma(a1, b23.x, acc[1][2]); acc[1][3] = fma(a1, b23.y, acc[1][3]);
    }
  }
  double* op = partial + (size_t)bz * 4096 * 128;
  #pragma unroll
  for (int i = 0; i < 2; ++i) {
    int row = m0 + ty * 2 + i;
    #pragma unroll
    for (int j = 0; j < 2; ++j) {
      op[(size_t)row * 128 + n0 + tx * 2 + j] = acc[i][j];
      op[(size_t)row * 128 + n0 + tx * 2 + 32 + j] = acc[i][j + 2];
    }
  }
}

// ------------------------------------------------------------- device: split-K reduce (8 slices)
__device__ __forceinline__ void dev_sel_reduce(int blk,
                                               const double* __restrict__ partial,
                                               const double* __restrict__ bias,
                                               double* __restrict__ qs64,
                                               double* __restrict__ ks64)
{
  const int idx = blk * 256 + threadIdx.x;
  const int row = idx >> 7, n = idx & 127;
  const size_t S = 4096 * 128;
  double v = partial[idx];
  #pragma unroll
  for (int z = 1; z < 8; ++z) v += partial[(size_t)z * S + idx];  // fixed order
  v += bias[n];
  if (n < 64) qs64[(size_t)row * 64 + n] = v;
  else        ks64[(size_t)row * 64 + (n - 64)] = v;
}

// ------------------------------------------------------------- fp64 transpose
__global__ __launch_bounds__(256) void k_transpose64(const double* __restrict__ in,
                                                     double* __restrict__ out)
{
  __shared__ double tile[32][33];
  const int bt = blockIdx.z;
  const int c0 = blockIdx.x * 32;
  const int r0 = blockIdx.y * 32;
  int tx = threadIdx.x & 31, ty = threadIdx.x >> 5;
  const double* ip = in + (size_t)bt * 2048 * 64;
  double* op = out + (size_t)bt * 64 * 2048;
  #pragma unroll
  for (int i = ty; i < 32; i += 8) tile[i][tx] = ip[(size_t)(r0 + i) * 64 + c0 + tx];
  __syncthreads();
  #pragma unroll
  for (int i = ty; i < 32; i += 8) op[(size_t)(c0 + i) * 2048 + r0 + tx] = tile[tx][i];
}

// ------------------------------------------------------------- k_score (R18-proven 32-row tiles)
// su keys as tiled fp64 GEMM: 32 rows x 512 keys, K=64; 64 fp64 acc/thread (static).
__global__ __launch_bounds__(256) void k_score(const double* __restrict__ qs,
                                               const double* __restrict__ ksT,
                                               u64* __restrict__ su)
{
  const int rt = blockIdx.x >> 2;       // row tile (32 rows)
  const int kc = blockIdx.x & 3;        // key chunk (512 keys)
  const int tmax = ((rt & 63) << 5) + 31;
  if (kc * 512 > tmax) return;          // causal: whole chunk beyond every row's t
  const int b = rt >> 6;
  const int tid = threadIdx.x;
  __shared__ double As[32 * 64];        // broadcast reads -> no conflicts
  {
    const double* qp = qs + (size_t)rt * 32 * 64;
    #pragma unroll
    for (int i = 0; i < 8; ++i) As[tid * 8 + i] = qp[tid * 8 + i];
  }
  __syncthreads();
  const int k0 = kc * 512 + tid;        // this thread's two keys
  const int k1 = k0 + 256;
  const double* kb = ksT + (size_t)b * 64 * 2048;
  double acc0[32] = {}, acc1[32] = {};
  for (int d = 0; d < 64; ++d) {
    const double b0 = kb[(size_t)d * 2048 + k0];
    const double b1 = kb[(size_t)d * 2048 + k1];
    #pragma unroll
    for (int r = 0; r < 32; ++r) {
      const double a = As[r * 64 + d];
      acc0[r] = fma(a, b0, acc0[r]);
      acc1[r] = fma(a, b1, acc1[r]);
    }
  }
  #pragma unroll
  for (int r = 0; r < 32; ++r) {
    const int row = rt * 32 + r;
    u64 u0 = (u64)__double_as_longlong(acc0[r]);
    u0 = (u0 >> 63) ? ~u0 : (u0 | 0x8000000000000000ull);
    su[(size_t)row * 2048 + k0] = u0;
    u64 u1 = (u64)__double_as_longlong(acc1[r]);
    u1 = (u1 >> 63) ? ~u1 : (u1 | 0x8000000000000000ull);
    su[(size_t)row * 2048 + k1] = u1;
  }
}

// ------------------------------------------------------------- device: fp16 MFMA GEMM
// Tile 128(M) x 64(N), BK=64, 4 waves, acc[4][2]. (Proven R14-R19.)
template <int MODE>
__device__ __forceinline__ void dev_gemm_bt(char* smem, int gbx, int gby, int nbx, int nby,
                                            const f16* __restrict__ A,
                                            const f16* __restrict__ BT,
                                            const float* __restrict__ bias,
                                            float* __restrict__ C, f16* __restrict__ Ch,
                                            f16* __restrict__ Kout, f16* __restrict__ Vout,
                                            const float* __restrict__ rc,
                                            const float* __restrict__ rs,
                                            int K, int lda, int ldb, int ldc)
{
  f16* As = (f16*)smem;             // 128*64
  f16* Bs = (f16*)smem + 128 * 64;  // 64*64
  const int tid = threadIdx.x;
  const int lane = tid & 63;
  const int wave = tid >> 6;
  int bx = gbx, by = gby;
  {
    const int nwg = nbx * nby;
    if ((nwg & 7) == 0) {
      const int bid = by * nbx + bx;
      const int cpx = nwg >> 3;
      const int sbid = (bid & 7) * cpx + (bid >> 3);
      bx = sbid % nbx;
      by = sbid / nbx;
    }
  }
  const int m0 = bx * 128, n0 = by * 64;
  const int wr = (wave >> 1) * 64, wc = (wave & 1) * 32;
  const int lrow = lane & 15;
  const int kgrp = (lane >> 4) * 8;
  f32x4 acc[4][2] = {};

  for (int k0 = 0; k0 < K; k0 += 64) {
    __syncthreads();
    #pragma unroll
    for (int it = 0; it < 4; ++it) {  // A: 128x64
      int c = it * 256 + tid;
      int r = c >> 3, c8 = (c & 7) * 8;
      int lbase = (it * 256 + (tid & 192)) * 8;
      const f16* ga = A + (size_t)(m0 + r) * lda + k0 + c8;
      __builtin_amdgcn_global_load_lds((const __attribute__((address_space(1))) u32*)ga,
                                       (__attribute__((address_space(3))) u32*)&As[lbase],
                                       16, 0, 0);
    }
    #pragma unroll
    for (int it = 0; it < 2; ++it) {  // B: 64x64
      int c = it * 256 + tid;
      int r = c >> 3, c8 = (c & 7) * 8;
      int lbase = (it * 256 + (tid & 192)) * 8;
      const f16* gb = BT + (size_t)(n0 + r) * ldb + k0 + c8;
      __builtin_amdgcn_global_load_lds((const __attribute__((address_space(1))) u32*)gb,
                                       (__attribute__((address_space(3))) u32*)&Bs[lbase],
                                       16, 0, 0);
    }
    __syncthreads();
    #pragma unroll
    for (int ks = 0; ks < 2; ++ks) {
      f16x8 af[4], bfr[2];
      #pragma unroll
      for (int m = 0; m < 4; ++m)
        af[m] = *(const f16x8*)&As[(wr + m * 16 + lrow) * 64 + ks * 32 + kgrp];
      #pragma unroll
      for (int n = 0; n < 2; ++n)
        bfr[n] = *(const f16x8*)&Bs[(wc + n * 16 + lrow) * 64 + ks * 32 + kgrp];
      #pragma unroll
      for (int m = 0; m < 4; ++m)
        #pragma unroll
        for (int n = 0; n < 2; ++n)
          acc[m][n] = __builtin_amdgcn_mfma_f32_16x16x32_f16(af[m], bfr[n], acc[m][n], 0, 0, 0);
    }
  }
  const int rbase = m0 + wr + (lane >> 4) * 4;  // C/D: col=lane&15, row=(lane>>4)*4+reg [m89]
  #pragma unroll
  for (int n = 0; n < 2; ++n) {
    int col = n0 + wc + n * 16 + lrow;
    float bv = bias ? bias[col] : 0.0f;
    const int ri = (col & 127) >> 1;  // rope pair index (MODE 2/3)
    #pragma unroll
    for (int m = 0; m < 4; ++m) {
      #pragma unroll
      for (int j = 0; j < 4; ++j) {
        int rowi = rbase + m * 16 + j;
        float v = acc[m][n][j] + bv;
        if (MODE == 0) {
          C[(size_t)rowi * ldc + col] = v;
        } else if (MODE == 1) {
          Ch[(size_t)rowi * ldc + col] = (f16)v;
        } else if (MODE == 2) {
          float vp = __shfl_xor(v, 1);
          int t = rowi & 2047;
          float c_ = rc[t * 64 + ri], s_ = rs[t * 64 + ri];
          float r_ = (lrow & 1) ? (vp * s_ + v * c_) : (v * c_ - vp * s_);
          Ch[(size_t)rowi * ldc + col] = (f16)r_;
        } else {  // MODE 3
          float vp = __shfl_xor(v, 1);
          if (n0 < 512) {
            int t = rowi & 2047;
            float c_ = rc[t * 64 + ri], s_ = rs[t * 64 + ri];
            float r_ = (lrow & 1) ? (vp * s_ + v * c_) : (v * c_ - vp * s_);
            Kout[(size_t)rowi * 512 + col] = (f16)r_;
          } else {
            Vout[(size_t)rowi * 512 + (col - 512)] = (f16)v;
          }
        }
      }
    }
  }
}

// ---------------------------------------------------------------- launch wrappers
// fusedA: sel_f64 splitK=8 (2048 blocks, fp64 VALU) || Wkd GEMM (256 blocks, MFMA)
__global__ __launch_bounds__(256) void k_fusedA(const float* __restrict__ x,
                                                const double* __restrict__ Bsel,
                                                double* __restrict__ partial,
                                                const f16* __restrict__ xh,
                                                const f16* __restrict__ WkdT,
                                                const float* __restrict__ bkd,
                                                f16* __restrict__ cbf)
{
  __shared__ __align__(16) char smem[25600];
  const int id = blockIdx.x;
  if (id < 2048) {
    dev_sel_f64(smem, id & 127, (id >> 7) & 1, id >> 8, x, Bsel, partial);
  } else {
    const int g = id - 2048;
    dev_gemm_bt<1>(smem, g & 31, g >> 5, 32, 8, xh, WkdT, bkd, nullptr, cbf,
                   nullptr, nullptr, nullptr, nullptr, 2048, 2048, 2048, 512);
  }
}

// fusedC: Wku GEMM (512 blocks) || sel_reduce (2048 blocks)
__global__ __launch_bounds__(256) void k_fusedC(const f16* __restrict__ cbf,
                                                const f16* __restrict__ WkuT,
                                                const float* __restrict__ bku,
                                                f16* __restrict__ krope, f16* __restrict__ vbf,
                                                const float* __restrict__ rc,
                                                const float* __restrict__ rs,
                                                const double* __restrict__ partial,
                                                const double* __restrict__ bsel,
                                                double* __restrict__ qs64,
                                                double* __restrict__ ks64)
{
  __shared__ __align__(16) char smem[24576];
  const int id = blockIdx.x;
  if (id < 512) {
    dev_gemm_bt<3>(smem, id & 31, id >> 5, 32, 16, cbf, WkuT, bku, nullptr, nullptr,
                   krope, vbf, rc, rs, 512, 512, 512, 1024);
  } else {
    dev_sel_reduce(id - 512, partial, bsel, qs64, ks64);
  }
}

// Wq GEMM standalone (MODE 2, grid 32x32)
__global__ __launch_bounds__(256) void k_gemmQ(const f16* __restrict__ xh,
                                               const f16* __restrict__ WqT,
                                               const float* __restrict__ bq,
                                               f16* __restrict__ qrope,
                                               const float* __restrict__ rc,
                                               const float* __restrict__ rs)
{
  __shared__ __align__(16) char smem[24576];
  dev_gemm_bt<2>(smem, blockIdx.x, blockIdx.y, 32, 32, xh, WqT, bq, nullptr, qrope,
                 nullptr, nullptr, rc, rs, 2048, 2048, 2048, 2048);
}

// Wo GEMM standalone (MODE 0, grid 32x32)
__global__ __launch_bounds__(256) void k_gemmO(const f16* __restrict__ A,
                                               const f16* __restrict__ BT,
                                               const float* __restrict__ bias,
                                               float* __restrict__ C)
{
  __shared__ __align__(16) char smem[24576];
  dev_gemm_bt<0>(smem, blockIdx.x, blockIdx.y, 32, 32, A, BT, bias, C, nullptr,
                 nullptr, nullptr, nullptr, nullptr, 2048, 2048, 2048, 2048);
}

// ------------------------------------------------------------- k_select: exact top-64
// 1 row/block, 256 threads. su staged LINEAR via global_load_lds (16B direct-to-LDS;
// the suX swizzle became pointless once hot loops read register-cached keys — LDS su
// is touched once per thread). Proven machinery: register key cache, wave-uniform
// hist aggregation, shfl scans + 4-wave combine, deterministic position-computed emit.
__global__ __launch_bounds__(256) void k_select(const u64* __restrict__ gsu,
                                                int* __restrict__ selcnt,
                                                int* __restrict__ selidx)
{
  const int row = blockIdx.x;
  const int t = row & 2047;
  const int tid = threadIdx.x;
  const int lane = tid & 63, wave = tid >> 6;
  int* outp = selidx + (size_t)row * 68;
  if (t < 64) {
    for (int jj = tid; jj <= t; jj += 256) outp[jj] = jj;
    if (tid == 0) selcnt[row] = t + 1;
    return;
  }
  __shared__ __align__(16) u64 su[2048];
  __shared__ unsigned hist[256];
  __shared__ unsigned wsum[4];
  __shared__ unsigned s_bsel, s_larger, s_cnt;
  __shared__ u64 s_thr;
  __shared__ int s_remfin;
  __shared__ int cand[128];
  __shared__ u64 ckey[128];

  {
    const u64* g = gsu + (size_t)row * 2048;
    #pragma unroll
    for (int it = 0; it < 4; ++it) {
      const u64* gp = g + (size_t)(it * 256 + tid) * 2;   // per-lane global src
      __builtin_amdgcn_global_load_lds(
          (const __attribute__((address_space(1))) u32*)gp,
          (__attribute__((address_space(3))) u32*)&su[(size_t)(it * 256 + (tid & 192)) * 2],
          16, 0, 0);  // wave-uniform LDS base + lane*16 = linear order
    }
  }
  __syncthreads();

  const int c0 = tid * 8;
  u64 kv[8]; bool kvv[8];
  #pragma unroll
  for (int e = 0; e < 8; ++e) {
    const int jj = c0 + e;
    kvv[e] = (jj <= t);
    kv[e] = kvv[e] ? su[jj] : 0;
  }

  u64 prefix = 0;
  int remaining = 64;
  int broke = 0, sh_final = 0;
  for (int byte = 7; byte >= 0; --byte) {
    const int sh = byte * 8;
    hist[tid] = 0;
    __syncthreads();
    {
      unsigned bn[8]; bool vl[8];
      #pragma unroll
      for (int e = 0; e < 8; ++e) {
        vl[e] = kvv[e] && ((byte == 7) || (((kv[e] ^ prefix) >> (sh + 8)) == 0));
        bn[e] = (unsigned)((kv[e] >> sh) & 255);
      }
      unsigned myBin = 0xFFFFFFFFu, cntLoc = 0;
      bool localSame = true;
      #pragma unroll
      for (int e = 0; e < 8; ++e) {
        if (vl[e]) {
          if (myBin == 0xFFFFFFFFu) myBin = bn[e];
          else if (bn[e] != myBin) localSame = false;
          ++cntLoc;
        }
      }
      const bool hasValid = (cntLoc > 0);
      unsigned vmin = hasValid ? myBin : 0xFFFFFFFFu;
      unsigned vmax = hasValid ? myBin : 0u;
      unsigned csum = cntLoc;
      #pragma unroll
      for (int off = 32; off; off >>= 1) {
        unsigned a = __shfl_xor(vmin, off); vmin = a < vmin ? a : vmin;
        unsigned bmx = __shfl_xor(vmax, off); vmax = bmx > vmax ? bmx : vmax;
        csum += __shfl_xor(csum, off);
      }
      const bool anyMixed = (__ballot(hasValid && !localSame) != 0ull);
      const bool anyValid = (__ballot(hasValid) != 0ull);
      if (!anyMixed && anyValid && vmin == vmax) {
        if (lane == 0) atomicAdd(&hist[vmin], csum);  // one atomic per wave
      } else if (hasValid) {
        #pragma unroll
        for (int e = 0; e < 8; ++e) {
          if (vl[e]) {
            bool first = true;
            #pragma unroll
            for (int p = 0; p < 8; ++p)
              if (p < e && vl[p] && bn[p] == bn[e]) first = false;
            if (first) {
              unsigned c = 0;
              #pragma unroll
              for (int q = 0; q < 8; ++q)
                if (q >= e && vl[q] && bn[q] == bn[e]) ++c;
              atomicAdd(&hist[bn[e]], c);
            }
          }
        }
      }
    }
    __syncthreads();
    // suffix-inclusive scan of hist (4 waves)
    const unsigned h = hist[tid];
    unsigned v = h;
    #pragma unroll
    for (int off = 1; off < 64; off <<= 1) {
      unsigned tv = __shfl_down(v, off);
      if (lane + off < 64) v += tv;
    }
    if (lane == 0) wsum[wave] = v;
    __syncthreads();
    unsigned add = 0;
    #pragma unroll
    for (int w = 0; w < 4; ++w)
      if (w > wave) add += wsum[w];
    const unsigned inc = v + add;
    const unsigned cumAbove = inc - h;
    __syncthreads();  // wsum reusable
    if ((int)cumAbove < remaining && (int)inc >= remaining) {
      s_bsel = (unsigned)tid;
      s_larger = cumAbove;
      s_cnt = inc - cumAbove;
    }
    __syncthreads();
    prefix |= ((u64)s_bsel << sh);
    remaining -= (int)s_larger;
    int cnt = (int)s_cnt;
    if (cnt <= 128) { broke = 1; sh_final = sh; break; }
  }
  u64 thr;
  int remfin;
  if (broke) {
    unsigned cg = 0;
    #pragma unroll
    for (int e = 0; e < 8; ++e)
      if (kvv[e] && (((kv[e] ^ prefix) >> sh_final) == 0)) ++cg;
    unsigned v = cg;
    #pragma unroll
    for (int off = 1; off < 64; off <<= 1) {
      unsigned tv = __shfl_up(v, off);
      if (lane >= off) v += tv;
    }
    __syncthreads();
    if (lane == 63) wsum[wave] = v;
    __syncthreads();
    unsigned add = 0, tot = 0;
    #pragma unroll
    for (int w = 0; w < 4; ++w) {
      tot += wsum[w];
      if (w < wave) add += wsum[w];
    }
    const int C = (int)tot;
    int pos = (int)(v + add - cg);
    __syncthreads();
    #pragma unroll
    for (int e = 0; e < 8; ++e)
      if (kvv[e] && (((kv[e] ^ prefix) >> sh_final) == 0)) cand[pos++] = c0 + e;
    __syncthreads();
    if (tid < C) ckey[tid] = su[cand[tid]];
    __syncthreads();
    if (tid < C) {
      u64 k = ckey[tid];
      int g = 0, eq = 0;
      for (int j = 0; j < C; ++j) {
        g += (ckey[j] > k) ? 1 : 0;
        eq += (ckey[j] == k) ? 1 : 0;
      }
      if (g < remaining && remaining <= g + eq) {
        s_thr = k;
        s_remfin = remaining - g;
      }
    }
    __syncthreads();
    thr = s_thr;
    remfin = s_remfin;
  } else {
    thr = prefix;
    remfin = remaining;
  }
  __syncthreads();
  // ---- deterministic emit: diag, greaters asc, first remfin ties asc ----
  unsigned cg = 0, ct_ = 0;
  #pragma unroll
  for (int e = 0; e < 8; ++e) {
    if (kvv[e]) {
      cg += (kv[e] > thr) ? 1u : 0u;
      ct_ += (kv[e] == thr) ? 1u : 0u;
    }
  }
  const unsigned pack = cg | (ct_ << 16);
  {
    unsigned v = pack;
    #pragma unroll
    for (int off = 1; off < 64; off <<= 1) {
      unsigned tv = __shfl_up(v, off);
      if (lane >= off) v += tv;
    }
    if (lane == 63) wsum[wave] = v;
    __syncthreads();
    unsigned add = 0, tot = 0;
    #pragma unroll
    for (int w = 0; w < 4; ++w) {
      tot += wsum[w];
      if (w < wave) add += wsum[w];
    }
    const unsigned excl = v + add - pack;
    __syncthreads();
    const unsigned Gtot = tot & 0xFFFFu;
    const u64 ut = su[t];
    const unsigned gt = (ut > thr) ? 1u : 0u;
    const unsigned tt = (ut == thr) ? 1u : 0u;
    const int GtotX = (int)(Gtot - gt);
    int gpos = (int)(excl & 0xFFFFu);
    int tpos = (int)(excl >> 16);
    #pragma unroll
    for (int e = 0; e < 8; ++e) {
      const int jj = c0 + e;
      if (!kvv[e]) break;
      if (kv[e] > thr) {
        if (jj != t) outp[1 + gpos] = jj;
        ++gpos;
      } else if (kv[e] == thr) {
        if (jj != t && tpos < remfin) outp[1 + GtotX + tpos] = jj;
        ++tpos;
      }
    }
    if (tid == 0) {
      outp[0] = t;
      const unsigned Ttot = tot >> 16;
      int tb = (int)(Ttot - tt);
      int emitT = tb < remfin ? tb : remfin;
      selcnt[row] = 1 + GtotX + emitT;  // 64 or 65
    }
  }
}

// ------------------------------------------------------------- sparse attention (R19 proven)
__global__ __launch_bounds__(256) void k_attn(const f16* __restrict__ qr,
                                              const f16* __restrict__ kr,
                                              const f16* __restrict__ vv,
                                              const int* __restrict__ selcnt,
                                              const int* __restrict__ selidx,
                                              f16* __restrict__ y)
{
  const int blk = blockIdx.x;  // row*4 + kvh
  const int row = blk >> 2, kvh = blk & 3;
  const int b = row >> 11;
  const int tid = threadIdx.x, lane = tid & 63, wave = tid >> 6;
  const int cnt = selcnt[row];
  __shared__ int sidx[68];
  __shared__ __align__(16) f16 Kl[65 * 128];   // chunk-XOR swizzled
  __shared__ __align__(16) f16 Vl[68 * 128];   // linear, rows [cnt,68) zeroed
  __shared__ __align__(4) f16 ph[4][72];       // P in f16, [cnt..72) zeroed
  if (tid < cnt) sidx[tid] = selidx[(size_t)row * 68 + tid];
  // Q in registers (wave-uniform addresses -> broadcast loads)
  const f16* qb = qr + ((size_t)row * 16 + kvh * 4 + wave) * 128;
  f16x8 qf[16];
  #pragma unroll
  for (int i = 0; i < 16; ++i) qf[i] = *(const f16x8*)&qb[i * 8];
  __syncthreads();  // sidx ready

  f16x8 kreg[5], vreg[5];
  int rr[5], cc[5]; bool vld[5];
  #pragma unroll
  for (int it = 0; it < 5; ++it) {
    const int c = it * 256 + tid;
    const int r = c >> 4, ch = c & 15;
    const bool ok = (r < cnt);
    const int rsafe = ok ? sidx[r] : sidx[0];
    const size_t kbase = ((size_t)(b * 2048 + rsafe)) * 512 + kvh * 128 + ch * 8;
    kreg[it] = *(const f16x8*)&kr[kbase];
    vreg[it] = *(const f16x8*)&vv[kbase];
    rr[it] = r; cc[it] = ch; vld[it] = ok;
  }
  #pragma unroll
  for (int it = 0; it < 5; ++it) {
    if (vld[it]) {
      *(f16x8*)&Kl[rr[it] * 128 + ((cc[it] ^ (rr[it] & 15)) * 8)] = kreg[it];
      *(f16x8*)&Vl[rr[it] * 128 + cc[it] * 8] = vreg[it];
    }
  }
  for (int i = tid; i < (68 - cnt) * 64; i += 256)
    ((u32*)Vl)[cnt * 64 + i] = 0u;
  __syncthreads();

  const float SCALE = 0.08838834764831845f;  // 1/sqrt(128)
  auto dotk = [&](int r) -> float {
    const int sw = r & 15;
    float s = 0.0f;
    #pragma unroll
    for (int i = 0; i < 16; ++i) {
      f16x8 k8 = *(const f16x8*)&Kl[r * 128 + ((i ^ sw) * 8)];
      f16x8 q8 = qf[i];
      #pragma unroll
      for (int e = 0; e < 4; ++e) {
        f16x2 ka; ka.x = k8[2 * e]; ka.y = k8[2 * e + 1];
        f16x2 qa; qa.x = q8[2 * e]; qa.y = q8[2 * e + 1];
        s = __builtin_amdgcn_fdot2(ka, qa, s, false);
      }
    }
    return s * SCALE;
  };

  float s1 = -__builtin_inff(), s2 = -__builtin_inff();
  if (lane < cnt) s1 = dotk(lane);
  if (lane + 64 < cnt) s2 = dotk(lane + 64);  // only lane 0, cnt==65
  float mx = fmaxf(s1, s2);
  #pragma unroll
  for (int off = 32; off; off >>= 1) mx = fmaxf(mx, __shfl_xor(mx, off));
  float p1 = (lane < cnt) ? __expf(s1 - mx) : 0.0f;
  float p2 = (lane + 64 < cnt) ? __expf(s2 - mx) : 0.0f;
  float l = p1 + p2;
  #pragma unroll
  for (int off = 32; off; off >>= 1) l += __shfl_xor(l, off);
  float linv = 1.0f / l;
  ph[wave][lane] = (f16)p1;
  if (lane == 0) ph[wave][64] = (f16)p2;
  if (lane >= 1 && lane < 8) ph[wave][64 + lane] = (f16)0.f;
  __syncthreads();

  float y0 = 0.0f, y1 = 0.0f;
  const int d2 = lane * 2;
  for (int j = 0; j < cnt; j += 2) {
    f16x2 pp = *(const f16x2*)&ph[wave][j];
    f16x2 va = *(const f16x2*)&Vl[(j + 0) * 128 + d2];
    f16x2 vb = *(const f16x2*)&Vl[(j + 1) * 128 + d2];
    f16x2 v0; v0.x = va.x; v0.y = vb.x;
    f16x2 v1; v1.x = va.y; v1.y = vb.y;
    y0 = __builtin_amdgcn_fdot2(pp, v0, y0, false);
    y1 = __builtin_amdgcn_fdot2(pp, v1, y1, false);
  }
  y0 *= linv; y1 *= linv;
  f16x2 o; o.x = (f16)y0; o.y = (f16)y1;
  *(f16x2*)&y[(size_t)row * 2048 + (kvh * 4 + wave) * 128 + d2] = o;
}

// ================================================================ launch
extern "C" void kernel_launch(void* const* d_in, const int* in_sizes, int n_in,
                              void* d_out, int out_size, void* d_ws, size_t ws_size,
                              hipStream_t stream)
{
  (void)in_sizes; (void)n_in; (void)out_size; (void)ws_size;
  const float* x   = (const float*)d_in[0];
  const float* Wq  = (const float*)d_in[1];
  const float* bq  = (const float*)d_in[2];
  const float* Wkd = (const float*)d_in[3];
  const float* bkd = (const float*)d_in[4];
  const float* Wku = (const float*)d_in[5];
  const float* bku = (const float*)d_in[6];
  const float* Wo  = (const float*)d_in[7];
  const float* bo  = (const float*)d_in[8];
  float* out = (float*)d_out;

  char* ws = (char*)d_ws;
  size_t o = 0;
  auto alloc = [&](size_t bytes) -> void* {
    o = (o + 255) & ~(size_t)255;
    void* p = ws + o;
    o += bytes;
    return p;
  };
  f16* WqT   = (f16*)alloc(2048ull * 2048 * 2);
  f16* WoT   = (f16*)alloc(2048ull * 2048 * 2);
  f16* WkdT  = (f16*)alloc(512ull * 2048 * 2);
  f16* WkuT  = (f16*)alloc(1024ull * 512 * 2);
  f16* xh    = (f16*)alloc(4096ull * 2048 * 2);
  f16* yh    = (f16*)alloc(4096ull * 2048 * 2);  // attention output
  f16* cbf   = (f16*)alloc(4096ull * 512 * 2);
  float* rc  = (float*)alloc(2048ull * 64 * 4);
  float* rs  = (float*)alloc(2048ull * 64 * 4);
  f16* qrope = (f16*)alloc(4096ull * 2048 * 2);
  f16* krope = (f16*)alloc(4096ull * 512 * 2);
  f16* vbf   = (f16*)alloc(4096ull * 512 * 2);
  int* selcnt = (int*)alloc(4096ull * 4);
  int* selidx = (int*)alloc(4096ull * 68 * 4);
  double* Bsel = (double*)alloc(2048ull * 128 * 8);
  double* bsel = (double*)alloc(128 * 8);
  double* qs64 = (double*)alloc(4096ull * 64 * 8);
  double* ks64 = (double*)alloc(4096ull * 64 * 8);
  double* ksT  = (double*)alloc(2ull * 64 * 2048 * 8);
  double* partial = (double*)alloc(8ull * 4096 * 128 * 8);  // 32 MiB (split-K=8)
  u64* gsu = (u64*)alloc(4096ull * 2048 * 8);               // 64 MiB score keys

  // --- megaP: all prep (transposes, cast, Bsel, bsel, rope tables) in one launch ---
  k_megaP<<<18945, 256, 0, stream>>>(Wq, WqT, Wkd, WkdT, Wku, WkuT, Wo, WoT, x, xh,
                                     Bsel, bq, bkd, bku, bsel, rc, rs);

  // --- fusedA: fp64 selector GEMM (split-K=8) || Wkd GEMM ---
  k_fusedA<<<2304, 256, 0, stream>>>(x, Bsel, partial, xh, WkdT, bkd, cbf);

  // --- fusedC: Wku GEMM (rope-k/V fused) || split-K reduce ---
  k_fusedC<<<2560, 256, 0, stream>>>(cbf, WkuT, bku, krope, vbf, rc, rs,
                                     partial, bsel, qs64, ks64);

  // --- ksT for coalesced score reads ---
  k_transpose64<<<dim3(2, 64, 2), 256, 0, stream>>>(ks64, ksT);

  // --- Wq GEMM (rope-q fused), then score (unfused: R19's fusion evicted ksT from L2) ---
  k_gemmQ<<<dim3(32, 32), 256, 0, stream>>>(xh, WqT, bq, qrope, rc, rs);
  k_score<<<512, 256, 0, stream>>>(qs64, ksT, gsu);

  // --- select (linear su, global_load_lds staging) ---
  k_select<<<4096, 256, 0, stream>>>(gsu, selcnt, selidx);

  // --- sparse attention (Q in registers) ---
  k_attn<<<16384, 256, 0, stream>>>(qrope, krope, vbf, selcnt, selidx, yh);

  // --- output projection ---
  k_gemmO<<<dim3(32, 32), 256, 0, stream>>>(yh, WoT, bo, out);
}